// Round 2
// baseline (1942.130 us; speedup 1.0000x reference)
//
#include <hip/hip_runtime.h>
#include <hip/hip_bf16.h>

// ToyMDNN on MI355X — round 2: fix round-1 abort.
//   * workspace: 160 MB (stats FIRST, then h fp32, then q/k/v bf16) — round 1
//     needed 269 MB with stats last, likely past ws_size.
//   * gemm LDS: 53 KB (64x128 tile, bf16-staged) — round 1 used 136 KB.
// N=1024 S=128 D=128 H=4 C=32 L=2.
//
// Dataflow:
//   h = BN(x @ linW^T)                       [gemm fp32-out + bn_apply in-place]
//   per layer l:
//     q/k/v raw = gemm(h) -> bf16 bufs, col stats fp32 (BN applied by consumer)
//     attn (BN on load) -> agg bf16 IN-PLACE into v buffer
//     out1 = LN(agg + h) -> kbuf bf16
//     ff_raw  = gemm(out1) -> vbuf bf16, stats
//     skip_raw= gemm(h)    -> qbuf bf16, stats
//     h = LN(out1 + BN(ff_raw)) + BN(skip_raw)    [fuse2 -> h fp32]
//   final layer: fuse2 emits only s==0 rows -> d_out (1024x128 fp32).
// GEMM biases are all skipped: adding a per-column constant cancels exactly
// through batch-norm.

typedef __attribute__((ext_vector_type(4))) short short4v;
typedef __attribute__((ext_vector_type(8))) short short8v;

#define NBATCH 1024
#define SEQ    128
#define DIM    128
#define NHEAD  4
#define CH     32
#define NLAYER 2
#define MTOT   (NBATCH*SEQ)          // 131072 rows
#define EPSF   1e-5f
#define INV_M  (1.0f/131072.0f)

__device__ __forceinline__ float bf2f(ushort s) {
  return __uint_as_float(((uint)s) << 16);
}
__device__ __forceinline__ ushort f2bf(float f) {
  uint u = __float_as_uint(f);
  return (ushort)((u + 0x7FFFu + ((u >> 16) & 1u)) >> 16);
}

// ---------------------------------------------------------------------------
// out[m][j] = sum_k A[m][k]*W[j][k]  (+ per-column sum/sumsq into stats).
// 64x128 tile per block, 256 threads, 4x8 micro-tile, K=128 in one shot.
// A and W staged TRANSPOSED in LDS as bf16 ([k][row]) so the k-loop does
// vectorized ds_read. fp32 accumulate. LDS = 53 KB.
// ---------------------------------------------------------------------------
template<bool ABF16, bool OBF16>
__global__ __launch_bounds__(256) void gemm_stats(
    const void* __restrict__ Ap, const float* __restrict__ W,
    void* __restrict__ outp, float* __restrict__ stats)
{
  __shared__ ushort At[128][72];    // [k][row]  stride 144 B (16B-mult)
  __shared__ ushort Wt[128][136];   // [k][col]  stride 272 B (16B-mult)
  __shared__ float csum[128], csq[128];
  const int tid = threadIdx.x;
  const int m0  = blockIdx.x * 64;

  if (tid < 128) { csum[tid] = 0.f; csq[tid] = 0.f; }

  if constexpr (ABF16) {
    const ushort* A = (const ushort*)Ap;
    for (int idx = tid; idx < 1024; idx += 256) {      // 64 rows x 16 chunks
      const int row = idx >> 4;
      const int kk  = (idx & 15) << 3;
      short8v a = *(const short8v*)(A + (long)(m0 + row) * DIM + kk);
#pragma unroll
      for (int i = 0; i < 8; ++i) At[kk + i][row] = (ushort)a[i];
    }
  } else {
    const float* A = (const float*)Ap;
    for (int idx = tid; idx < 2048; idx += 256) {      // 64 rows x 32 chunks
      const int row = idx >> 5;
      const int kk  = (idx & 31) << 2;
      float4 a = *(const float4*)(A + (long)(m0 + row) * DIM + kk);
      At[kk + 0][row] = f2bf(a.x); At[kk + 1][row] = f2bf(a.y);
      At[kk + 2][row] = f2bf(a.z); At[kk + 3][row] = f2bf(a.w);
    }
  }
  for (int idx = tid; idx < 4096; idx += 256) {        // 128 rows x 32 chunks
    const int row = idx >> 5;
    const int kk  = (idx & 31) << 2;
    float4 w = *(const float4*)(W + row * DIM + kk);
    Wt[kk + 0][row] = f2bf(w.x); Wt[kk + 1][row] = f2bf(w.y);
    Wt[kk + 2][row] = f2bf(w.z); Wt[kk + 3][row] = f2bf(w.w);
  }
  __syncthreads();

  const int tx = tid & 15, ty = tid >> 4;
  const int c0 = tx * 8, r0 = ty * 4;

  float acc[4][8];
#pragma unroll
  for (int i = 0; i < 4; ++i)
#pragma unroll
    for (int j = 0; j < 8; ++j) acc[i][j] = 0.f;

#pragma unroll 4
  for (int k = 0; k < 128; ++k) {
    short4v av = *(const short4v*)&At[k][r0];
    short8v wv = *(const short8v*)&Wt[k][c0];
    float a[4], w[8];
#pragma unroll
    for (int i = 0; i < 4; ++i) a[i] = bf2f((ushort)av[i]);
#pragma unroll
    for (int j = 0; j < 8; ++j) w[j] = bf2f((ushort)wv[j]);
#pragma unroll
    for (int i = 0; i < 4; ++i)
#pragma unroll
      for (int j = 0; j < 8; ++j) acc[i][j] += a[i] * w[j];
  }

  float ps[8], pq[8];
#pragma unroll
  for (int j = 0; j < 8; ++j) { ps[j] = 0.f; pq[j] = 0.f; }
#pragma unroll
  for (int i = 0; i < 4; ++i) {
    const long orow = (long)(m0 + r0 + i) * DIM + c0;
    if constexpr (OBF16) {
      short8v o;
#pragma unroll
      for (int j = 0; j < 8; ++j) o[j] = (short)f2bf(acc[i][j]);
      *(short8v*)((ushort*)outp + orow) = o;
    } else {
      float* outf = (float*)outp;
      *(float4*)(outf + orow)     = make_float4(acc[i][0], acc[i][1], acc[i][2], acc[i][3]);
      *(float4*)(outf + orow + 4) = make_float4(acc[i][4], acc[i][5], acc[i][6], acc[i][7]);
    }
#pragma unroll
    for (int j = 0; j < 8; ++j) { ps[j] += acc[i][j]; pq[j] += acc[i][j] * acc[i][j]; }
  }
  // reduce over the 4 ty-groups inside each wave (lane bits 4..5)
#pragma unroll
  for (int j = 0; j < 8; ++j) {
    ps[j] += __shfl_xor(ps[j], 16); ps[j] += __shfl_xor(ps[j], 32);
    pq[j] += __shfl_xor(pq[j], 16); pq[j] += __shfl_xor(pq[j], 32);
  }
  if ((ty & 3) == 0) {
#pragma unroll
    for (int j = 0; j < 8; ++j) {
      atomicAdd(&csum[c0 + j], ps[j]);
      atomicAdd(&csq[c0 + j],  pq[j]);
    }
  }
  __syncthreads();
  if (tid < 128) {
    atomicAdd(&stats[tid],       csum[tid]);
    atomicAdd(&stats[128 + tid], csq[tid]);
  }
}

// ---------------------------------------------------------------------------
// In-place BN apply for h (fp32, many consumers).
// ---------------------------------------------------------------------------
__global__ __launch_bounds__(256) void bn_apply(
    float* __restrict__ x, const float* __restrict__ st,
    const float* __restrict__ g, const float* __restrict__ b)
{
  __shared__ float sc[128], bi[128];
  const int tid = threadIdx.x;
  if (tid < 128) {
    float mean = st[tid] * INV_M;
    float var  = st[128 + tid] * INV_M - mean * mean;
    float s = rsqrtf(var + EPSF) * g[tid];
    sc[tid] = s;
    bi[tid] = b[tid] - mean * s;
  }
  __syncthreads();
  const long total4 = (long)MTOT * DIM / 4;
  for (long i = (long)blockIdx.x * 256 + tid; i < total4; i += (long)gridDim.x * 256) {
    float4 vv = ((const float4*)x)[i];
    const int c = (int)((i * 4) & 127);
    vv.x = vv.x * sc[c + 0] + bi[c + 0];
    vv.y = vv.y * sc[c + 1] + bi[c + 1];
    vv.z = vv.z * sc[c + 2] + bi[c + 2];
    vv.w = vv.w * sc[c + 3] + bi[c + 3];
    ((float4*)x)[i] = vv;
  }
}

// ---------------------------------------------------------------------------
// Attention, one (n, head) per block. q/k/v bf16 raw; BN applied on load.
// Logits are alpha*mask (0 where masked) then softmax over all 128 — exact
// reference semantics. agg written bf16 IN-PLACE into the v buffer (each
// block reads only its own slice into LDS before any store).
// ---------------------------------------------------------------------------
__global__ __launch_bounds__(256) void attn_kernel(
    const ushort* __restrict__ q, const ushort* k_in, const ushort* v_in,
    const float* __restrict__ mask,
    const float* __restrict__ qst, const float* __restrict__ kst, const float* __restrict__ vst,
    const float* __restrict__ qg, const float* __restrict__ qbb,
    const float* __restrict__ kg, const float* __restrict__ kbb,
    const float* __restrict__ vg, const float* __restrict__ vbb,
    ushort* out)
{
  __shared__ float kn[128][32];
  __shared__ float vn[128][32];
  __shared__ float qsc[32], qbi[32], ksc[32], kbi[32], vsc[32], vbi[32];
  const int tid = threadIdx.x;
  const int n   = blockIdx.x >> 2;
  const int hh  = blockIdx.x & 3;
  const int c0  = hh * CH;

  if (tid < 96) {
    const int which = tid >> 5, c = tid & 31, j = c0 + c;
    const float* st = (which == 0) ? qst : (which == 1) ? kst : vst;
    const float* g  = (which == 0) ? qg  : (which == 1) ? kg  : vg;
    const float* b  = (which == 0) ? qbb : (which == 1) ? kbb : vbb;
    float mean = st[j] * INV_M;
    float var  = st[128 + j] * INV_M - mean * mean;
    float s  = rsqrtf(var + EPSF) * g[j];
    float bi = b[j] - mean * s;
    if (which == 0)      { qsc[c] = s; qbi[c] = bi; }
    else if (which == 1) { ksc[c] = s; kbi[c] = bi; }
    else                 { vsc[c] = s; vbi[c] = bi; }
  }
  __syncthreads();

  const long base = (long)n * SEQ * DIM + c0;
  for (int idx = tid; idx < 512; idx += 256) {    // 128 rows x 4 chunks of 8
    const int t2 = idx >> 2, cc = (idx & 3) << 3;
    short8v kv = *(const short8v*)(k_in + base + (long)t2 * DIM + cc);
    short8v vv = *(const short8v*)(v_in + base + (long)t2 * DIM + cc);
#pragma unroll
    for (int i = 0; i < 8; ++i) {
      kn[t2][cc + i] = bf2f((ushort)kv[i]) * ksc[cc + i] + kbi[cc + i];
      vn[t2][cc + i] = bf2f((ushort)vv[i]) * vsc[cc + i] + vbi[cc + i];
    }
  }
  __syncthreads();

  const int s_ = tid >> 1, half = tid & 1;
  float qreg[32];
  {
    const ushort* qrow = q + base + (long)s_ * DIM;
#pragma unroll
    for (int cc = 0; cc < 32; cc += 8) {
      short8v qv = *(const short8v*)(qrow + cc);
#pragma unroll
      for (int i = 0; i < 8; ++i)
        qreg[cc + i] = bf2f((ushort)qv[i]) * qsc[cc + i] + qbi[cc + i];
    }
  }

  const float* mrow = mask + ((long)n * SEQ + s_) * SEQ + half * 64;
  float sc[64];
  float mx = -1e30f;
#pragma unroll
  for (int j = 0; j < 64; ++j) {
    const float* kr = kn[half * 64 + j];
    float d = 0.f;
#pragma unroll
    for (int cc = 0; cc < 32; cc += 4) {
      float4 kv = *(const float4*)(kr + cc);
      d += qreg[cc] * kv.x + qreg[cc + 1] * kv.y + qreg[cc + 2] * kv.z + qreg[cc + 3] * kv.w;
    }
    d *= mrow[j];
    sc[j] = d;
    mx = fmaxf(mx, d);
  }
  mx = fmaxf(mx, __shfl_xor(mx, 1));
  float se = 0.f;
#pragma unroll
  for (int j = 0; j < 64; ++j) {
    float p = __expf(sc[j] - mx);
    sc[j] = p;
    se += p;
  }
  se += __shfl_xor(se, 1);
  const float inv = 1.f / se;

  float agg[32];
#pragma unroll
  for (int c = 0; c < 32; ++c) agg[c] = 0.f;
#pragma unroll
  for (int j = 0; j < 64; ++j) {
    const float p = sc[j];
    const float* vr = vn[half * 64 + j];
#pragma unroll
    for (int cc = 0; cc < 32; cc += 4) {
      float4 vv = *(const float4*)(vr + cc);
      agg[cc + 0] += p * vv.x;
      agg[cc + 1] += p * vv.y;
      agg[cc + 2] += p * vv.z;
      agg[cc + 3] += p * vv.w;
    }
  }
#pragma unroll
  for (int c = 0; c < 32; ++c) agg[c] += __shfl_xor(agg[c], 1);

  ushort* orow = out + base + (long)s_ * DIM + half * 16;
  short8v o0, o1;
#pragma unroll
  for (int i = 0; i < 8; ++i) {
    o0[i] = (short)f2bf(agg[half * 16 + i] * inv);
    o1[i] = (short)f2bf(agg[half * 16 + 8 + i] * inv);
  }
  *(short8v*)(orow)     = o0;
  *(short8v*)(orow + 8) = o1;
}

// ---------------------------------------------------------------------------
// out1 = LN(agg + h).  agg bf16, h fp32, out bf16. One wave per row.
// ---------------------------------------------------------------------------
__global__ __launch_bounds__(256) void ln_add(
    const ushort* __restrict__ a, const float* __restrict__ b,
    const float* __restrict__ g, const float* __restrict__ bb,
    ushort* __restrict__ out)
{
  const int lane = threadIdx.x & 63;
  const int wid  = (blockIdx.x * 256 + threadIdx.x) >> 6;
  const int NW   = gridDim.x * 4;
  const int c = lane * 2;
  const float g0 = g[c], g1 = g[c + 1], be0 = bb[c], be1 = bb[c + 1];
  for (int m = wid; m < MTOT; m += NW) {
    const long off = (long)m * DIM + c;
    uint av = *(const uint*)(a + off);
    float2 hv = *(const float2*)(b + off);
    float y0 = bf2f((ushort)(av & 0xFFFFu)) + hv.x;
    float y1 = bf2f((ushort)(av >> 16))     + hv.y;
    float s = y0 + y1, sq = y0 * y0 + y1 * y1;
#pragma unroll
    for (int o = 32; o; o >>= 1) { s += __shfl_xor(s, o); sq += __shfl_xor(sq, o); }
    const float mean = s * (1.f / 128.f);
    const float var  = sq * (1.f / 128.f) - mean * mean;
    const float rs   = rsqrtf(var + EPSF);
    float o0 = (y0 - mean) * rs * g0 + be0;
    float o1 = (y1 - mean) * rs * g1 + be1;
    *(uint*)(out + off) = (uint)f2bf(o0) | ((uint)f2bf(o1) << 16);
  }
}

// ---------------------------------------------------------------------------
// h_new = LN(out1 + BN_ff(ff_raw)) + BN_skip(skip_raw).  All inputs bf16,
// output fp32. FINAL=true: only rows m = n*S, compact to (N,128) -> d_out.
// ---------------------------------------------------------------------------
template <bool FINAL>
__global__ __launch_bounds__(256) void fuse2_k(
    const ushort* __restrict__ t1, const ushort* __restrict__ ffr, const ushort* __restrict__ skr,
    const float* __restrict__ fst, const float* __restrict__ sst,
    const float* __restrict__ fg, const float* __restrict__ fb,
    const float* __restrict__ sg, const float* __restrict__ sb,
    const float* __restrict__ lg, const float* __restrict__ lb,
    float* __restrict__ out)
{
  const int lane = threadIdx.x & 63;
  const int c = lane * 2;
  float fs0, fbias0, fs1, fbias1, ss0, sbias0, ss1, sbias1;
  {
    float m0 = fst[c] * INV_M;
    float v0 = fst[128 + c] * INV_M - m0 * m0;
    fs0 = rsqrtf(v0 + EPSF) * fg[c];       fbias0 = fb[c] - m0 * fs0;
    float m1 = fst[c + 1] * INV_M;
    float v1 = fst[128 + c + 1] * INV_M - m1 * m1;
    fs1 = rsqrtf(v1 + EPSF) * fg[c + 1];   fbias1 = fb[c + 1] - m1 * fs1;
    float n0 = sst[c] * INV_M;
    float w0 = sst[128 + c] * INV_M - n0 * n0;
    ss0 = rsqrtf(w0 + EPSF) * sg[c];       sbias0 = sb[c] - n0 * ss0;
    float n1 = sst[c + 1] * INV_M;
    float w1 = sst[128 + c + 1] * INV_M - n1 * n1;
    ss1 = rsqrtf(w1 + EPSF) * sg[c + 1];   sbias1 = sb[c + 1] - n1 * ss1;
  }
  const float lg0 = lg[c], lg1 = lg[c + 1], lb0 = lb[c], lb1 = lb[c + 1];
  const int wid = (blockIdx.x * 256 + threadIdx.x) >> 6;
  const int NW  = gridDim.x * 4;
  const int ROWS = FINAL ? NBATCH : MTOT;
  for (int r = wid; r < ROWS; r += NW) {
    const long m   = FINAL ? (long)r * SEQ : (long)r;
    const long off = m * DIM + c;
    uint tv = *(const uint*)(t1 + off);
    uint fv = *(const uint*)(ffr + off);
    uint sv = *(const uint*)(skr + off);
    float t0 = bf2f((ushort)(tv & 0xFFFFu)), t1_ = bf2f((ushort)(tv >> 16));
    float f0 = bf2f((ushort)(fv & 0xFFFFu)), f1 = bf2f((ushort)(fv >> 16));
    float s0 = bf2f((ushort)(sv & 0xFFFFu)), s1 = bf2f((ushort)(sv >> 16));
    float y0 = t0 + f0 * fs0 + fbias0;
    float y1 = t1_ + f1 * fs1 + fbias1;
    float s = y0 + y1, sq = y0 * y0 + y1 * y1;
#pragma unroll
    for (int o = 32; o; o >>= 1) { s += __shfl_xor(s, o); sq += __shfl_xor(sq, o); }
    const float mean = s * (1.f / 128.f);
    const float var  = sq * (1.f / 128.f) - mean * mean;
    const float rs   = rsqrtf(var + EPSF);
    float o0 = (y0 - mean) * rs * lg0 + lb0 + (s0 * ss0 + sbias0);
    float o1 = (y1 - mean) * rs * lg1 + lb1 + (s1 * ss1 + sbias1);
    const long ooff = FINAL ? ((long)r * DIM + c) : off;
    *(float2*)(out + ooff) = make_float2(o0, o1);
  }
}

// ---------------------------------------------------------------------------
extern "C" void kernel_launch(void* const* d_in, const int* in_sizes, int n_in,
                              void* d_out, int out_size, void* d_ws, size_t ws_size,
                              hipStream_t stream)
{
  (void)in_sizes; (void)n_in; (void)out_size; (void)ws_size;
  const float* x    = (const float*)d_in[0];
  const float* mask = (const float*)d_in[1];
  const float* linW = (const float*)d_in[2];
  const float* ing  = (const float*)d_in[4];
  const float* inb  = (const float*)d_in[5];
  const float* qW   = (const float*)d_in[6];
  const float* qg   = (const float*)d_in[8];
  const float* qb   = (const float*)d_in[9];
  const float* kW   = (const float*)d_in[10];
  const float* kg   = (const float*)d_in[12];
  const float* kb   = (const float*)d_in[13];
  const float* vW   = (const float*)d_in[14];
  const float* vg   = (const float*)d_in[16];
  const float* vb   = (const float*)d_in[17];
  const float* lng  = (const float*)d_in[18];
  const float* lnb  = (const float*)d_in[19];
  const float* ffW  = (const float*)d_in[20];
  const float* ffg  = (const float*)d_in[22];
  const float* ffb  = (const float*)d_in[23];
  const float* skW  = (const float*)d_in[24];
  const float* skg  = (const float*)d_in[26];
  const float* skb  = (const float*)d_in[27];

  const long MD = (long)MTOT * DIM;            // 16,777,216 elements
  float*  stats = (float*)d_ws;                // 11 slots x 256 f (front of ws)
  float*  h     = (float*)d_ws + 16384;        // 64 KB pad, fp32 h
  ushort* qbuf  = (ushort*)(h + MD);
  ushort* kbuf  = qbuf + MD;
  ushort* vbuf  = kbuf + MD;                   // total ~160.1 MB

  hipMemsetAsync(stats, 0, 11 * 256 * sizeof(float), stream);

  gemm_stats<false, false><<<MTOT / 64, 256, 0, stream>>>(x, linW, h, stats);
  bn_apply<<<1024, 256, 0, stream>>>(h, stats, ing, inb);

  for (int l = 0; l < NLAYER; ++l) {
    const int woff = l * DIM * DIM;
    const int poff = l * DIM;
    float* stq = stats + (1 + 5 * l) * 256;
    float* stk = stats + (2 + 5 * l) * 256;
    float* stv = stats + (3 + 5 * l) * 256;
    float* stf = stats + (4 + 5 * l) * 256;
    float* sts = stats + (5 + 5 * l) * 256;

    gemm_stats<false, true><<<MTOT / 64, 256, 0, stream>>>(h, qW + woff, qbuf, stq);
    gemm_stats<false, true><<<MTOT / 64, 256, 0, stream>>>(h, kW + woff, kbuf, stk);
    gemm_stats<false, true><<<MTOT / 64, 256, 0, stream>>>(h, vW + woff, vbuf, stv);

    attn_kernel<<<NBATCH * NHEAD, 256, 0, stream>>>(
        qbuf, kbuf, vbuf, mask, stq, stk, stv,
        qg + poff, qb + poff, kg + poff, kb + poff, vg + poff, vb + poff,
        vbuf /* agg in-place */);

    ln_add<<<1024, 256, 0, stream>>>(vbuf, h, lng + poff, lnb + poff, kbuf);

    gemm_stats<true, true><<<MTOT / 64, 256, 0, stream>>>(kbuf, ffW + woff, vbuf, stf);
    gemm_stats<false, true><<<MTOT / 64, 256, 0, stream>>>(h, skW + woff, qbuf, sts);

    if (l < NLAYER - 1) {
      fuse2_k<false><<<1024, 256, 0, stream>>>(
          kbuf, vbuf, qbuf, stf, sts,
          ffg + poff, ffb + poff, skg + poff, skb + poff,
          lng + poff, lnb + poff, h);
    } else {
      fuse2_k<true><<<64, 256, 0, stream>>>(
          kbuf, vbuf, qbuf, stf, sts,
          ffg + poff, ffb + poff, skg + poff, skb + poff,
          lng + poff, lnb + poff, (float*)d_out);
    }
  }
}

// Round 4
// 857.252 us; speedup vs baseline: 2.2655x; 2.2655x over previous
//
#include <hip/hip_runtime.h>
#include <hip/hip_bf16.h>

// ToyMDNN on MI355X — round 4: fix P-tile swizzle overflow in attn_mfma
// (write used add-after-XOR, read used full-index XOR -> P scrambled for
// rows with (sl&7) large). GEMM/QK^T/PV fragment mappings are self-
// consistent (shared logical-k permutation on A and B) and unchanged.
// N=1024 S=128 D=128 H=4 C=32 L=2.
//
// Dataflow:
//   h = BN(x @ linW^T)                        [gemm fp32-out + bn_apply]
//   per layer: q/k/v raw = gemm(h) bf16 + col stats (BN applied by consumer)
//              attn (BN on load) -> agg bf16 IN-PLACE into v buffer
//              out1 = LN(agg + h) -> kbuf bf16
//              ff_raw = gemm(out1) -> vbuf; skip_raw = gemm(h) -> qbuf
//              h = LN(out1 + BN(ff)) + BN(skip)   [fuse2; final layer -> d_out]
// GEMM biases all cancel exactly through batch-norm.
//
// MFMA 32x32x16 bf16, D layout (m74/m101-verified):
//   D: col = lane&31, row = (reg&3) + 8*(reg>>2) + 4*(lane>>5)
// A/B loaded with logical k = kt*16 + (lane>>5)*8 + j on BOTH operands
// (self-consistent under any fixed HW k-permutation).
// LDS XOR swizzle on 256B-stride rows: full ushort idx ^ ((row&7)<<3).

typedef __attribute__((ext_vector_type(8))) short short8v;
typedef __attribute__((ext_vector_type(16))) float f32x16;

#define NBATCH 1024
#define SEQ    128
#define DIM    128
#define NLAYER 2
#define MTOT   (NBATCH*SEQ)
#define EPSF   1e-5f
#define INV_M  (1.0f/131072.0f)

__device__ __forceinline__ float bf2f(ushort s) {
  return __uint_as_float(((uint)s) << 16);
}
__device__ __forceinline__ ushort f2bf(float f) {
  uint u = __float_as_uint(f);
  return (ushort)((u + 0x7FFFu + ((u >> 16) & 1u)) >> 16);
}

// ---------------------------------------------------------------------------
// out[m][j] = sum_k A[m][k]*W[j][k]  + per-column sum/sumsq into stats.
// Block: 128 rows x 128 cols, K=128 one shot, 4 waves (wave w: rows w*32..+31).
// W staged bf16 in LDS [j][k] swizzled; A-frags loaded direct from global.
// ---------------------------------------------------------------------------
template<bool ABF16, bool OBF16>
__global__ __launch_bounds__(256) void gemm_mfma(
    const void* __restrict__ Ap, const float* __restrict__ W,
    void* __restrict__ outp, float* __restrict__ stats)
{
  __shared__ ushort Wt[128 * 128];
  __shared__ float csum[128], csq[128];
  const int tid = threadIdx.x;
  const int lane = tid & 63, wid = tid >> 6;
  const int hi = lane >> 5, ln = lane & 31;
  const long m0 = (long)blockIdx.x * 128;

  if (tid < 128) { csum[tid] = 0.f; csq[tid] = 0.f; }

  // stage W (fp32 -> bf16), swizzled
  for (int idx = tid; idx < 2048; idx += 256) {
    const int j = idx & 127, oc = (idx >> 7) * 8;
    float4 w0 = *(const float4*)(W + j * DIM + oc);
    float4 w1 = *(const float4*)(W + j * DIM + oc + 4);
    short8v v;
    v[0] = (short)f2bf(w0.x); v[1] = (short)f2bf(w0.y);
    v[2] = (short)f2bf(w0.z); v[3] = (short)f2bf(w0.w);
    v[4] = (short)f2bf(w1.x); v[5] = (short)f2bf(w1.y);
    v[6] = (short)f2bf(w1.z); v[7] = (short)f2bf(w1.w);
    *(short8v*)&Wt[(j * 128 + oc) ^ ((j & 7) << 3)] = v;
  }
  __syncthreads();

  // A-fragments direct from global: row = m0 + wid*32 + ln, 8 k-chunks
  const long arow = m0 + wid * 32 + ln;
  short8v afr[8];
  if constexpr (ABF16) {
    const ushort* ar = (const ushort*)Ap + arow * DIM + hi * 8;
#pragma unroll
    for (int kt = 0; kt < 8; ++kt) afr[kt] = *(const short8v*)(ar + kt * 16);
  } else {
    const float* ar = (const float*)Ap + arow * DIM + hi * 8;
#pragma unroll
    for (int kt = 0; kt < 8; ++kt) {
      float4 a0 = *(const float4*)(ar + kt * 16);
      float4 a1 = *(const float4*)(ar + kt * 16 + 4);
      short8v v;
      v[0] = (short)f2bf(a0.x); v[1] = (short)f2bf(a0.y);
      v[2] = (short)f2bf(a0.z); v[3] = (short)f2bf(a0.w);
      v[4] = (short)f2bf(a1.x); v[5] = (short)f2bf(a1.y);
      v[6] = (short)f2bf(a1.z); v[7] = (short)f2bf(a1.w);
      afr[kt] = v;
    }
  }

  f32x16 acc[4];
#pragma unroll
  for (int nt = 0; nt < 4; ++nt)
#pragma unroll
    for (int r = 0; r < 16; ++r) acc[nt][r] = 0.f;

#pragma unroll
  for (int kt = 0; kt < 8; ++kt) {
#pragma unroll
    for (int nt = 0; nt < 4; ++nt) {
      short8v b = *(const short8v*)&Wt[((nt * 32 + ln) * 128 + kt * 16 + hi * 8) ^ ((ln & 7) << 3)];
      acc[nt] = __builtin_amdgcn_mfma_f32_32x32x16_bf16(afr[kt], b, acc[nt], 0, 0, 0);
    }
  }

  float ps[4], pq[4];
#pragma unroll
  for (int nt = 0; nt < 4; ++nt) { ps[nt] = 0.f; pq[nt] = 0.f; }
#pragma unroll
  for (int nt = 0; nt < 4; ++nt) {
    const int col = nt * 32 + ln;
#pragma unroll
    for (int r = 0; r < 16; ++r) {
      const float v = acc[nt][r];
      ps[nt] += v; pq[nt] += v * v;
      const long row = m0 + wid * 32 + (r & 3) + 8 * (r >> 2) + 4 * hi;
      if constexpr (OBF16) ((ushort*)outp)[row * DIM + col] = f2bf(v);
      else                 ((float*)outp)[row * DIM + col] = v;
    }
  }
#pragma unroll
  for (int nt = 0; nt < 4; ++nt) {
    ps[nt] += __shfl_xor(ps[nt], 32);
    pq[nt] += __shfl_xor(pq[nt], 32);
  }
  if (hi == 0) {
#pragma unroll
    for (int nt = 0; nt < 4; ++nt) {
      atomicAdd(&csum[nt * 32 + ln], ps[nt]);
      atomicAdd(&csq[nt * 32 + ln], pq[nt]);
    }
  }
  __syncthreads();
  if (tid < 128) {
    atomicAdd(&stats[tid],       csum[tid]);
    atomicAdd(&stats[128 + tid], csq[tid]);
  }
}

// ---------------------------------------------------------------------------
// In-place BN apply for h (fp32).
// ---------------------------------------------------------------------------
__global__ __launch_bounds__(256) void bn_apply(
    float* __restrict__ x, const float* __restrict__ st,
    const float* __restrict__ g, const float* __restrict__ b)
{
  __shared__ float sc[128], bi[128];
  const int tid = threadIdx.x;
  if (tid < 128) {
    float mean = st[tid] * INV_M;
    float var  = st[128 + tid] * INV_M - mean * mean;
    float s = rsqrtf(var + EPSF) * g[tid];
    sc[tid] = s;
    bi[tid] = b[tid] - mean * s;
  }
  __syncthreads();
  const long total4 = (long)MTOT * DIM / 4;
  for (long i = (long)blockIdx.x * 256 + tid; i < total4; i += (long)gridDim.x * 256) {
    float4 vv = ((const float4*)x)[i];
    const int c = (int)((i * 4) & 127);
    vv.x = vv.x * sc[c + 0] + bi[c + 0];
    vv.y = vv.y * sc[c + 1] + bi[c + 1];
    vv.z = vv.z * sc[c + 2] + bi[c + 2];
    vv.w = vv.w * sc[c + 3] + bi[c + 3];
    ((float4*)x)[i] = vv;
  }
}

// ---------------------------------------------------------------------------
// MFMA attention. One block per n; wave = head. BN applied on load.
// S = Q·K^T (mask-mult in D-regs, softmax across 32-lane half), P via LDS,
// O = P·V with V^T staged swizzled in LDS. agg written in-place to v buffer.
// ---------------------------------------------------------------------------
__global__ __launch_bounds__(256) void attn_mfma(
    const ushort* __restrict__ q, const ushort* __restrict__ k_in, const ushort* v_in,
    const float* __restrict__ mask,
    const float* __restrict__ qst, const float* __restrict__ kst, const float* __restrict__ vst,
    const float* __restrict__ qg, const float* __restrict__ qbb,
    const float* __restrict__ kg, const float* __restrict__ kbb,
    const float* __restrict__ vg, const float* __restrict__ vbb,
    ushort* out)
{
  __shared__ ushort Vt[128 * 128];   // [c_all][t] swizzled, normalized bf16
  __shared__ ushort Pl[4 * 32 * 128];// per-wave P [s_local][t] swizzled
  __shared__ float scl[6][128];      // q s/b, k s/b, v s/b

  const int tid = threadIdx.x;
  const int lane = tid & 63, wid = tid >> 6;
  const int hi = lane >> 5, ln = lane & 31;
  const int n = blockIdx.x;
  const long base = (long)n * SEQ * DIM;

  if (tid < 128) {
    const int c = tid;
    float m, v, s;
    m = qst[c] * INV_M; v = qst[128 + c] * INV_M - m * m;
    s = rsqrtf(v + EPSF) * qg[c];  scl[0][c] = s; scl[1][c] = qbb[c] - m * s;
    m = kst[c] * INV_M; v = kst[128 + c] * INV_M - m * m;
    s = rsqrtf(v + EPSF) * kg[c];  scl[2][c] = s; scl[3][c] = kbb[c] - m * s;
    m = vst[c] * INV_M; v = vst[128 + c] * INV_M - m * m;
    s = rsqrtf(v + EPSF) * vg[c];  scl[4][c] = s; scl[5][c] = vbb[c] - m * s;
  }
  __syncthreads();

  // stage V^T normalized (write banks spread by t: 2-way)
  for (int it = 0; it < 8; ++it) {
    const int idx = it * 256 + tid;
    const int t = idx & 127, c0 = (idx >> 7) * 8;
    short8v vv = *(const short8v*)(v_in + base + (long)t * DIM + c0);
#pragma unroll
    for (int i = 0; i < 8; ++i) {
      float f = bf2f((ushort)vv[i]) * scl[4][c0 + i] + scl[5][c0 + i];
      Vt[((c0 + i) * 128 + t) ^ (i << 3)] = f2bf(f);   // (c0+i)&7 == i
    }
  }
  __syncthreads();

  const int hh = wid;
  const int cb = hh * 32;

  // K B-fragments (normalized), cached across all row-tiles
  short8v kfr[4][2];
#pragma unroll
  for (int nt = 0; nt < 4; ++nt)
#pragma unroll
    for (int kt = 0; kt < 2; ++kt) {
      short8v raw = *(const short8v*)(k_in + base + (long)(nt * 32 + ln) * DIM + cb + kt * 16 + hi * 8);
      short8v f;
#pragma unroll
      for (int i = 0; i < 8; ++i) {
        const int c = cb + kt * 16 + hi * 8 + i;
        f[i] = (short)f2bf(bf2f((ushort)raw[i]) * scl[2][c] + scl[3][c]);
      }
      kfr[nt][kt] = f;
    }
  // V B-fragments from LDS, cached
  short8v vfr[8];
#pragma unroll
  for (int kt = 0; kt < 8; ++kt)
    vfr[kt] = *(const short8v*)&Vt[((cb + ln) * 128 + kt * 16 + hi * 8) ^ ((ln & 7) << 3)];

  const float* mbase = mask + (long)n * SEQ * SEQ;
  const int pb = wid * 4096;

  for (int mt = 0; mt < 4; ++mt) {
    const int s0 = mt * 32;
    // Q A-fragments (normalized)
    short8v qfr[2];
#pragma unroll
    for (int kt = 0; kt < 2; ++kt) {
      short8v raw = *(const short8v*)(q + base + (long)(s0 + ln) * DIM + cb + kt * 16 + hi * 8);
      short8v f;
#pragma unroll
      for (int i = 0; i < 8; ++i) {
        const int c = cb + kt * 16 + hi * 8 + i;
        f[i] = (short)f2bf(bf2f((ushort)raw[i]) * scl[0][c] + scl[1][c]);
      }
      qfr[kt] = f;
    }

    f32x16 sc_[4];
#pragma unroll
    for (int nt = 0; nt < 4; ++nt)
#pragma unroll
      for (int r = 0; r < 16; ++r) sc_[nt][r] = 0.f;
#pragma unroll
    for (int nt = 0; nt < 4; ++nt) {
      sc_[nt] = __builtin_amdgcn_mfma_f32_32x32x16_bf16(qfr[0], kfr[nt][0], sc_[nt], 0, 0, 0);
      sc_[nt] = __builtin_amdgcn_mfma_f32_32x32x16_bf16(qfr[1], kfr[nt][1], sc_[nt], 0, 0, 0);
    }

    // mask multiply (reference: softmax(alpha*mask))
#pragma unroll
    for (int r = 0; r < 16; ++r) {
      const int s = s0 + (r & 3) + 8 * (r >> 2) + 4 * hi;
      const float* mr = mbase + (long)s * SEQ + ln;
#pragma unroll
      for (int nt = 0; nt < 4; ++nt) sc_[nt][r] *= mr[nt * 32];
    }

    // softmax per row (row lives in one 32-lane half) + write P
#pragma unroll
    for (int r = 0; r < 16; ++r) {
      float mx = fmaxf(fmaxf(sc_[0][r], sc_[1][r]), fmaxf(sc_[2][r], sc_[3][r]));
      mx = fmaxf(mx, __shfl_xor(mx, 1));
      mx = fmaxf(mx, __shfl_xor(mx, 2));
      mx = fmaxf(mx, __shfl_xor(mx, 4));
      mx = fmaxf(mx, __shfl_xor(mx, 8));
      mx = fmaxf(mx, __shfl_xor(mx, 16));
      float e0 = __expf(sc_[0][r] - mx);
      float e1 = __expf(sc_[1][r] - mx);
      float e2 = __expf(sc_[2][r] - mx);
      float e3 = __expf(sc_[3][r] - mx);
      float sum = e0 + e1 + e2 + e3;
      sum += __shfl_xor(sum, 1);
      sum += __shfl_xor(sum, 2);
      sum += __shfl_xor(sum, 4);
      sum += __shfl_xor(sum, 8);
      sum += __shfl_xor(sum, 16);
      const float inv = 1.f / sum;
      const int sl = (r & 3) + 8 * (r >> 2) + 4 * hi;
      const int rowb = pb + sl * 128;          // 128-aligned row base
      const int sw = (sl & 7) << 3;            // XOR confined to bits 3..5
      Pl[rowb + (( 0 + ln) ^ sw)] = f2bf(e0 * inv);
      Pl[rowb + ((32 + ln) ^ sw)] = f2bf(e1 * inv);
      Pl[rowb + ((64 + ln) ^ sw)] = f2bf(e2 * inv);
      Pl[rowb + ((96 + ln) ^ sw)] = f2bf(e3 * inv);
    }
    __threadfence_block();   // drain LDS writes before cross-lane P reads

    // O = P·V
    f32x16 o;
#pragma unroll
    for (int r = 0; r < 16; ++r) o[r] = 0.f;
#pragma unroll
    for (int kt = 0; kt < 8; ++kt) {
      short8v pa = *(const short8v*)&Pl[pb + ((ln * 128 + kt * 16 + hi * 8) ^ ((ln & 7) << 3))];
      o = __builtin_amdgcn_mfma_f32_32x32x16_bf16(pa, vfr[kt], o, 0, 0, 0);
    }
    // store O (in-place into v buffer: all V reads completed before barrier)
#pragma unroll
    for (int r = 0; r < 16; ++r) {
      const int s = s0 + (r & 3) + 8 * (r >> 2) + 4 * hi;
      out[base + (long)s * DIM + cb + ln] = f2bf(o[r]);
    }
  }
}

// ---------------------------------------------------------------------------
// out1 = LN(agg + h). agg bf16, h fp32, out bf16. One wave per row.
// ---------------------------------------------------------------------------
__global__ __launch_bounds__(256) void ln_add(
    const ushort* __restrict__ a, const float* __restrict__ b,
    const float* __restrict__ g, const float* __restrict__ bb,
    ushort* __restrict__ out)
{
  const int lane = threadIdx.x & 63;
  const int wid  = (blockIdx.x * 256 + threadIdx.x) >> 6;
  const int NW   = gridDim.x * 4;
  const int c = lane * 2;
  const float g0 = g[c], g1 = g[c + 1], be0 = bb[c], be1 = bb[c + 1];
  for (int m = wid; m < MTOT; m += NW) {
    const long off = (long)m * DIM + c;
    uint av = *(const uint*)(a + off);
    float2 hv = *(const float2*)(b + off);
    float y0 = bf2f((ushort)(av & 0xFFFFu)) + hv.x;
    float y1 = bf2f((ushort)(av >> 16))     + hv.y;
    float s = y0 + y1, sq = y0 * y0 + y1 * y1;
#pragma unroll
    for (int o = 32; o; o >>= 1) { s += __shfl_xor(s, o); sq += __shfl_xor(sq, o); }
    const float mean = s * (1.f / 128.f);
    const float var  = sq * (1.f / 128.f) - mean * mean;
    const float rs   = rsqrtf(var + EPSF);
    float o0 = (y0 - mean) * rs * g0 + be0;
    float o1 = (y1 - mean) * rs * g1 + be1;
    *(uint*)(out + off) = (uint)f2bf(o0) | ((uint)f2bf(o1) << 16);
  }
}

// ---------------------------------------------------------------------------
// h_new = LN(out1 + BN_ff(ff_raw)) + BN_skip(skip_raw). Inputs bf16, out fp32.
// FINAL=true: only rows m=n*S, compact (N,128) -> d_out.
// ---------------------------------------------------------------------------
template <bool FINAL>
__global__ __launch_bounds__(256) void fuse2_k(
    const ushort* __restrict__ t1, const ushort* __restrict__ ffr, const ushort* __restrict__ skr,
    const float* __restrict__ fst, const float* __restrict__ sst,
    const float* __restrict__ fg, const float* __restrict__ fb,
    const float* __restrict__ sg, const float* __restrict__ sb,
    const float* __restrict__ lg, const float* __restrict__ lb,
    float* __restrict__ out)
{
  const int lane = threadIdx.x & 63;
  const int c = lane * 2;
  float fs0, fbias0, fs1, fbias1, ss0, sbias0, ss1, sbias1;
  {
    float m0 = fst[c] * INV_M;
    float v0 = fst[128 + c] * INV_M - m0 * m0;
    fs0 = rsqrtf(v0 + EPSF) * fg[c];       fbias0 = fb[c] - m0 * fs0;
    float m1 = fst[c + 1] * INV_M;
    float v1 = fst[128 + c + 1] * INV_M - m1 * m1;
    fs1 = rsqrtf(v1 + EPSF) * fg[c + 1];   fbias1 = fb[c + 1] - m1 * fs1;
    float n0 = sst[c] * INV_M;
    float w0 = sst[128 + c] * INV_M - n0 * n0;
    ss0 = rsqrtf(w0 + EPSF) * sg[c];       sbias0 = sb[c] - n0 * ss0;
    float n1 = sst[c + 1] * INV_M;
    float w1 = sst[128 + c + 1] * INV_M - n1 * n1;
    ss1 = rsqrtf(w1 + EPSF) * sg[c + 1];   sbias1 = sb[c + 1] - n1 * ss1;
  }
  const float lg0 = lg[c], lg1 = lg[c + 1], lb0 = lb[c], lb1 = lb[c + 1];
  const int wid = (blockIdx.x * 256 + threadIdx.x) >> 6;
  const int NW  = gridDim.x * 4;
  const int ROWS = FINAL ? NBATCH : MTOT;
  for (int r = wid; r < ROWS; r += NW) {
    const long m   = FINAL ? (long)r * SEQ : (long)r;
    const long off = m * DIM + c;
    uint tv = *(const uint*)(t1 + off);
    uint fv = *(const uint*)(ffr + off);
    uint sv = *(const uint*)(skr + off);
    float t0 = bf2f((ushort)(tv & 0xFFFFu)), t1_ = bf2f((ushort)(tv >> 16));
    float f0 = bf2f((ushort)(fv & 0xFFFFu)), f1 = bf2f((ushort)(fv >> 16));
    float s0 = bf2f((ushort)(sv & 0xFFFFu)), s1 = bf2f((ushort)(sv >> 16));
    float y0 = t0 + f0 * fs0 + fbias0;
    float y1 = t1_ + f1 * fs1 + fbias1;
    float s = y0 + y1, sq = y0 * y0 + y1 * y1;
#pragma unroll
    for (int o = 32; o; o >>= 1) { s += __shfl_xor(s, o); sq += __shfl_xor(sq, o); }
    const float mean = s * (1.f / 128.f);
    const float var  = sq * (1.f / 128.f) - mean * mean;
    const float rs   = rsqrtf(var + EPSF);
    float o0 = (y0 - mean) * rs * lg0 + lb0 + (s0 * ss0 + sbias0);
    float o1 = (y1 - mean) * rs * lg1 + lb1 + (s1 * ss1 + sbias1);
    const long ooff = FINAL ? ((long)r * DIM + c) : off;
    *(float2*)(out + ooff) = make_float2(o0, o1);
  }
}

// ---------------------------------------------------------------------------
extern "C" void kernel_launch(void* const* d_in, const int* in_sizes, int n_in,
                              void* d_out, int out_size, void* d_ws, size_t ws_size,
                              hipStream_t stream)
{
  (void)in_sizes; (void)n_in; (void)out_size; (void)ws_size;
  const float* x    = (const float*)d_in[0];
  const float* mask = (const float*)d_in[1];
  const float* linW = (const float*)d_in[2];
  const float* ing  = (const float*)d_in[4];
  const float* inb  = (const float*)d_in[5];
  const float* qW   = (const float*)d_in[6];
  const float* qg   = (const float*)d_in[8];
  const float* qb   = (const float*)d_in[9];
  const float* kW   = (const float*)d_in[10];
  const float* kg   = (const float*)d_in[12];
  const float* kb   = (const float*)d_in[13];
  const float* vW   = (const float*)d_in[14];
  const float* vg   = (const float*)d_in[16];
  const float* vb   = (const float*)d_in[17];
  const float* lng  = (const float*)d_in[18];
  const float* lnb  = (const float*)d_in[19];
  const float* ffW  = (const float*)d_in[20];
  const float* ffg  = (const float*)d_in[22];
  const float* ffb  = (const float*)d_in[23];
  const float* skW  = (const float*)d_in[24];
  const float* skg  = (const float*)d_in[26];
  const float* skb  = (const float*)d_in[27];

  const long MD = (long)MTOT * DIM;
  float*  stats = (float*)d_ws;
  float*  h     = (float*)d_ws + 16384;
  ushort* qbuf  = (ushort*)(h + MD);
  ushort* kbuf  = qbuf + MD;
  ushort* vbuf  = kbuf + MD;

  hipMemsetAsync(stats, 0, 11 * 256 * sizeof(float), stream);

  gemm_mfma<false, false><<<MTOT / 128, 256, 0, stream>>>(x, linW, h, stats);
  bn_apply<<<1024, 256, 0, stream>>>(h, stats, ing, inb);

  for (int l = 0; l < NLAYER; ++l) {
    const int woff = l * DIM * DIM;
    const int poff = l * DIM;
    float* stq = stats + (1 + 5 * l) * 256;
    float* stk = stats + (2 + 5 * l) * 256;
    float* stv = stats + (3 + 5 * l) * 256;
    float* stf = stats + (4 + 5 * l) * 256;
    float* sts = stats + (5 + 5 * l) * 256;

    gemm_mfma<false, true><<<MTOT / 128, 256, 0, stream>>>(h, qW + woff, qbuf, stq);
    gemm_mfma<false, true><<<MTOT / 128, 256, 0, stream>>>(h, kW + woff, kbuf, stk);
    gemm_mfma<false, true><<<MTOT / 128, 256, 0, stream>>>(h, vW + woff, vbuf, stv);

    attn_mfma<<<NBATCH, 256, 0, stream>>>(
        qbuf, kbuf, vbuf, mask, stq, stk, stv,
        qg + poff, qb + poff, kg + poff, kb + poff, vg + poff, vb + poff,
        vbuf /* agg in-place */);

    ln_add<<<1024, 256, 0, stream>>>(vbuf, h, lng + poff, lnb + poff, kbuf);

    gemm_mfma<true, true><<<MTOT / 128, 256, 0, stream>>>(kbuf, ffW + woff, vbuf, stf);
    gemm_mfma<false, true><<<MTOT / 128, 256, 0, stream>>>(h, skW + woff, qbuf, sts);

    if (l < NLAYER - 1) {
      fuse2_k<false><<<1024, 256, 0, stream>>>(
          kbuf, vbuf, qbuf, stf, sts,
          ffg + poff, ffb + poff, skg + poff, skb + poff,
          lng + poff, lnb + poff, h);
    } else {
      fuse2_k<true><<<64, 256, 0, stream>>>(
          kbuf, vbuf, qbuf, stf, sts,
          ffg + poff, ffb + poff, skg + poff, skb + poff,
          lng + poff, lnb + poff, (float*)d_out);
    }
  }
}

// Round 5
// 754.498 us; speedup vs baseline: 2.5741x; 1.1362x over previous
//
#include <hip/hip_runtime.h>
#include <hip/hip_bf16.h>

// ToyMDNN on MI355X — round 5.
//  * attn: swapped QK^T (S^T = mfma(K,Q)) -> in-lane softmax, no P-LDS roundtrip,
//    V raw in LDS (BN folded into epilogue via sum(P)=1), mask direct from global
//    (L1-resident). LDS 36.8KB, launch_bounds(256,4) -> 4 blocks/CU.
//  * weights pre-converted to bf16 swizzled layout once (stored in d_out tail,
//    overwritten by the final kernel); QKV GEMM fused (A read once, W dbuf).
// N=1024 S=128 D=128 H=4 C=32 L=2. GEMM biases cancel through batch-norm.

typedef __attribute__((ext_vector_type(8))) short short8v;
typedef __attribute__((ext_vector_type(16))) float f32x16;

#define NBATCH 1024
#define SEQ    128
#define DIM    128
#define NLAYER 2
#define MTOT   (NBATCH*SEQ)
#define EPSF   1e-5f
#define INV_M  (1.0f/131072.0f)

__device__ __forceinline__ float bf2f(ushort s) {
  return __uint_as_float(((uint)s) << 16);
}
__device__ __forceinline__ ushort f2bf(float f) {
  uint u = __float_as_uint(f);
  return (ushort)((u + 0x7FFFu + ((u >> 16) & 1u)) >> 16);
}

struct WPtrs { const float* p[11]; };

// ---------------------------------------------------------------------------
// One-time: convert 11 weight matrices fp32 -> bf16 in the swizzled layout the
// GEMM LDS stage expects (linear copy then). dst[m*16384 + j*128 + (k8 ^ ((j&7)<<3))].
// ---------------------------------------------------------------------------
__global__ __launch_bounds__(256) void prep_w(WPtrs wp, ushort* __restrict__ dst)
{
  const int gid = blockIdx.x * 256 + threadIdx.x;   // 88*256 = 22528 = 11*2048
  const int m = gid >> 11;
  const int rem = gid & 2047;
  const int j = rem >> 4, kc = rem & 15;
  const float* src = wp.p[m];
  float4 a = *(const float4*)(src + j * DIM + kc * 8);
  float4 b = *(const float4*)(src + j * DIM + kc * 8 + 4);
  short8v v;
  v[0] = (short)f2bf(a.x); v[1] = (short)f2bf(a.y);
  v[2] = (short)f2bf(a.z); v[3] = (short)f2bf(a.w);
  v[4] = (short)f2bf(b.x); v[5] = (short)f2bf(b.y);
  v[6] = (short)f2bf(b.z); v[7] = (short)f2bf(b.w);
  *(short8v*)(dst + m * 16384 + j * 128 + ((kc * 8) ^ ((j & 7) << 3))) = v;
}

// ---------------------------------------------------------------------------
// Single GEMM: out[m][j] = sum_k A[m][k]*W[j][k] + column stats.
// Grid 512, 2 tiles of 128 rows per block. W (bf16, pre-swizzled) staged once.
// ---------------------------------------------------------------------------
template<bool ABF16, bool OBF16>
__global__ __launch_bounds__(256) void gemm_one(
    const void* __restrict__ Ap, const ushort* __restrict__ Wsw,
    void* __restrict__ outp, float* __restrict__ stats)
{
  __shared__ ushort Wt[16384];
  __shared__ float csum[128], csq[128];
  const int tid = threadIdx.x;
  const int lane = tid & 63, wid = tid >> 6;
  const int hi = lane >> 5, ln = lane & 31;

  for (int i = tid; i < 2048; i += 256)
    ((short8v*)Wt)[i] = ((const short8v*)Wsw)[i];
  if (tid < 128) { csum[tid] = 0.f; csq[tid] = 0.f; }
  __syncthreads();

  float ps[4], pq[4];
#pragma unroll
  for (int nt = 0; nt < 4; ++nt) { ps[nt] = 0.f; pq[nt] = 0.f; }

#pragma unroll
  for (int t = 0; t < 2; ++t) {
    const long m0 = ((long)blockIdx.x * 2 + t) * 128;
    const long arow = m0 + wid * 32 + ln;
    short8v afr[8];
    if constexpr (ABF16) {
      const ushort* ar = (const ushort*)Ap + arow * DIM + hi * 8;
#pragma unroll
      for (int kt = 0; kt < 8; ++kt) afr[kt] = *(const short8v*)(ar + kt * 16);
    } else {
      const float* ar = (const float*)Ap + arow * DIM + hi * 8;
#pragma unroll
      for (int kt = 0; kt < 8; ++kt) {
        float4 a0 = *(const float4*)(ar + kt * 16);
        float4 a1 = *(const float4*)(ar + kt * 16 + 4);
        short8v v;
        v[0] = (short)f2bf(a0.x); v[1] = (short)f2bf(a0.y);
        v[2] = (short)f2bf(a0.z); v[3] = (short)f2bf(a0.w);
        v[4] = (short)f2bf(a1.x); v[5] = (short)f2bf(a1.y);
        v[6] = (short)f2bf(a1.z); v[7] = (short)f2bf(a1.w);
        afr[kt] = v;
      }
    }

    f32x16 acc[4];
#pragma unroll
    for (int nt = 0; nt < 4; ++nt)
#pragma unroll
      for (int r = 0; r < 16; ++r) acc[nt][r] = 0.f;
#pragma unroll
    for (int kt = 0; kt < 8; ++kt)
#pragma unroll
      for (int nt = 0; nt < 4; ++nt) {
        short8v b = *(const short8v*)&Wt[((nt * 32 + ln) * 128 + kt * 16 + hi * 8) ^ ((ln & 7) << 3)];
        acc[nt] = __builtin_amdgcn_mfma_f32_32x32x16_bf16(afr[kt], b, acc[nt], 0, 0, 0);
      }

#pragma unroll
    for (int nt = 0; nt < 4; ++nt) {
      const int col = nt * 32 + ln;
#pragma unroll
      for (int r = 0; r < 16; ++r) {
        const float v = acc[nt][r];
        ps[nt] += v; pq[nt] += v * v;
        const long row = m0 + wid * 32 + (r & 3) + 8 * (r >> 2) + 4 * hi;
        if constexpr (OBF16) ((ushort*)outp)[row * DIM + col] = f2bf(v);
        else                 ((float*)outp)[row * DIM + col] = v;
      }
    }
  }

#pragma unroll
  for (int nt = 0; nt < 4; ++nt) {
    ps[nt] += __shfl_xor(ps[nt], 32);
    pq[nt] += __shfl_xor(pq[nt], 32);
  }
  if (hi == 0) {
#pragma unroll
    for (int nt = 0; nt < 4; ++nt) {
      atomicAdd(&csum[nt * 32 + ln], ps[nt]);
      atomicAdd(&csq[nt * 32 + ln], pq[nt]);
    }
  }
  __syncthreads();
  if (tid < 128) {
    atomicAdd(&stats[tid],       csum[tid]);
    atomicAdd(&stats[128 + tid], csq[tid]);
  }
}

// ---------------------------------------------------------------------------
// Fused QKV GEMM: A (fp32 h) read once per tile; 3 weight matrices cycled
// through a double-buffered LDS stage. Grid 512, 2 tiles/block.
// ---------------------------------------------------------------------------
__global__ __launch_bounds__(256) void gemm_qkv(
    const float* __restrict__ A, const ushort* __restrict__ Wsw,
    ushort* __restrict__ o0, ushort* __restrict__ o1, ushort* __restrict__ o2,
    float* __restrict__ st0, float* __restrict__ st1, float* __restrict__ st2)
{
  __shared__ ushort Wt[2][16384];
  __shared__ float csum[128], csq[128];
  const int tid = threadIdx.x;
  const int lane = tid & 63, wid = tid >> 6;
  const int hi = lane >> 5, ln = lane & 31;

  for (int i = tid; i < 2048; i += 256)
    ((short8v*)Wt[0])[i] = ((const short8v*)Wsw)[i];
  if (tid < 128) { csum[tid] = 0.f; csq[tid] = 0.f; }

  float ps[3][4], pq[3][4];
#pragma unroll
  for (int w = 0; w < 3; ++w)
#pragma unroll
    for (int nt = 0; nt < 4; ++nt) { ps[w][nt] = 0.f; pq[w][nt] = 0.f; }

  __syncthreads();

  short8v afr[8];
#pragma unroll
  for (int step = 0; step < 6; ++step) {
    const int t = step / 3, w = step % 3;
    const long m0 = ((long)blockIdx.x * 2 + t) * 128;
    if (w == 0) {
      const float* ar = A + (m0 + wid * 32 + ln) * DIM + hi * 8;
#pragma unroll
      for (int kt = 0; kt < 8; ++kt) {
        float4 a0 = *(const float4*)(ar + kt * 16);
        float4 a1 = *(const float4*)(ar + kt * 16 + 4);
        short8v v;
        v[0] = (short)f2bf(a0.x); v[1] = (short)f2bf(a0.y);
        v[2] = (short)f2bf(a0.z); v[3] = (short)f2bf(a0.w);
        v[4] = (short)f2bf(a1.x); v[5] = (short)f2bf(a1.y);
        v[6] = (short)f2bf(a1.z); v[7] = (short)f2bf(a1.w);
        afr[kt] = v;
      }
    }
    if (step < 5) {
      const int wn = (step + 1) % 3;
      const short8v* src = (const short8v*)(Wsw + wn * 16384);
      short8v* dst = (short8v*)Wt[(step + 1) & 1];
      for (int i = tid; i < 2048; i += 256) dst[i] = src[i];
    }

    f32x16 acc[4];
#pragma unroll
    for (int nt = 0; nt < 4; ++nt)
#pragma unroll
      for (int r = 0; r < 16; ++r) acc[nt][r] = 0.f;
    const ushort* wt = Wt[step & 1];
#pragma unroll
    for (int kt = 0; kt < 8; ++kt)
#pragma unroll
      for (int nt = 0; nt < 4; ++nt) {
        short8v b = *(const short8v*)&wt[((nt * 32 + ln) * 128 + kt * 16 + hi * 8) ^ ((ln & 7) << 3)];
        acc[nt] = __builtin_amdgcn_mfma_f32_32x32x16_bf16(afr[kt], b, acc[nt], 0, 0, 0);
      }

    ushort* outp = (w == 0) ? o0 : (w == 1) ? o1 : o2;
#pragma unroll
    for (int nt = 0; nt < 4; ++nt) {
      const int col = nt * 32 + ln;
#pragma unroll
      for (int r = 0; r < 16; ++r) {
        const float v = acc[nt][r];
        ps[w][nt] += v; pq[w][nt] += v * v;
        const long row = m0 + wid * 32 + (r & 3) + 8 * (r >> 2) + 4 * hi;
        outp[row * DIM + col] = f2bf(v);
      }
    }
    __syncthreads();
  }

  // stats reduction, one round per w (csum re-zeroed by same thread after use)
#pragma unroll
  for (int w = 0; w < 3; ++w) {
    float* st = (w == 0) ? st0 : (w == 1) ? st1 : st2;
    float lps[4], lpq[4];
#pragma unroll
    for (int nt = 0; nt < 4; ++nt) {
      lps[nt] = ps[w][nt] + __shfl_xor(ps[w][nt], 32);
      lpq[nt] = pq[w][nt] + __shfl_xor(pq[w][nt], 32);
    }
    if (hi == 0) {
#pragma unroll
      for (int nt = 0; nt < 4; ++nt) {
        atomicAdd(&csum[nt * 32 + ln], lps[nt]);
        atomicAdd(&csq[nt * 32 + ln],  lpq[nt]);
      }
    }
    __syncthreads();
    if (tid < 128) {
      atomicAdd(&st[tid],       csum[tid]);
      atomicAdd(&st[128 + tid], csq[tid]);
      csum[tid] = 0.f; csq[tid] = 0.f;
    }
    __syncthreads();
  }
}

// ---------------------------------------------------------------------------
// In-place BN apply for h (fp32).
// ---------------------------------------------------------------------------
__global__ __launch_bounds__(256) void bn_apply(
    float* __restrict__ x, const float* __restrict__ st,
    const float* __restrict__ g, const float* __restrict__ b)
{
  __shared__ float sc[128], bi[128];
  const int tid = threadIdx.x;
  if (tid < 128) {
    float mean = st[tid] * INV_M;
    float var  = st[128 + tid] * INV_M - mean * mean;
    float s = rsqrtf(var + EPSF) * g[tid];
    sc[tid] = s;
    bi[tid] = b[tid] - mean * s;
  }
  __syncthreads();
  const long total4 = (long)MTOT * DIM / 4;
  for (long i = (long)blockIdx.x * 256 + tid; i < total4; i += (long)gridDim.x * 256) {
    float4 vv = ((const float4*)x)[i];
    const int c = (int)((i * 4) & 127);
    vv.x = vv.x * sc[c + 0] + bi[c + 0];
    vv.y = vv.y * sc[c + 1] + bi[c + 1];
    vv.z = vv.z * sc[c + 2] + bi[c + 2];
    vv.w = vv.w * sc[c + 3] + bi[c + 3];
    ((float4*)x)[i] = vv;
  }
}

// ---------------------------------------------------------------------------
// Attention, swapped-QK^T form. One block per n; wave = head.
// S^T = mfma(A=K_norm, B=Q_norm): lane owns row s=lane&31 (its hi-half of t).
// Softmax in-lane (+1 shfl_xor(32) pair). PV consumes D-regs directly as
// A-frags; V staged RAW in LDS with slot permutation matching the D-reg
// order; V's batch-norm is folded into the epilogue using sum(P)=1:
//   out[s][c] = vs[c] * (P·V_raw)[s][c] + vb[c].
// Mask (0/1 fp32) read directly from global (L1-resident per block).
// agg written in-place into the v buffer (V fully staged before barrier).
// ---------------------------------------------------------------------------
__global__ __launch_bounds__(256, 4) void attn_mfma2(
    const ushort* __restrict__ q, const ushort* __restrict__ k_in, const ushort* v_in,
    const float* __restrict__ mask,
    const float* __restrict__ qst, const float* __restrict__ kst, const float* __restrict__ vst,
    const float* __restrict__ qg, const float* __restrict__ qbb,
    const float* __restrict__ kg, const float* __restrict__ kbb,
    const float* __restrict__ vg, const float* __restrict__ vbb,
    ushort* out)
{
  __shared__ ushort Vp[128 * 136];    // [c][slot(t)] raw bf16, stride 136 (16B-aligned)
  __shared__ float qsc[128], qbi[128], ksc[128], kbi[128];

  const int tid = threadIdx.x;
  const int lane = tid & 63, wid = tid >> 6;
  const int hi = lane >> 5, ln = lane & 31;
  const int n = blockIdx.x;
  const long base = (long)n * SEQ * DIM;
  const int cb = wid * 32;

  if (tid < 128) {
    const int c = tid;
    float m, v, s;
    m = qst[c] * INV_M; v = qst[128 + c] * INV_M - m * m;
    s = rsqrtf(v + EPSF) * qg[c];  qsc[c] = s; qbi[c] = qbb[c] - m * s;
    m = kst[c] * INV_M; v = kst[128 + c] * INV_M - m * m;
    s = rsqrtf(v + EPSF) * kg[c];  ksc[c] = s; kbi[c] = kbb[c] - m * s;
  }
  // per-lane V affine for output column c = cb + ln
  const int cc = cb + ln;
  float vs, vb0;
  {
    float m = vst[cc] * INV_M;
    float v = vst[128 + cc] * INV_M - m * m;
    vs = rsqrtf(v + EPSF) * vg[cc];
    vb0 = vbb[cc] - m * vs;
  }

  // stage V raw into permuted slots: Vp[c][slot(t)] = V[t][c]
  for (int it = 0; it < 8; ++it) {
    const int idx = it * 256 + tid;
    const int t = idx & 127, c0 = (idx >> 7) * 8;
    short8v vv = *(const short8v*)(v_in + base + (long)t * DIM + c0);
    const int tl = t & 31;
    const int kt = tl >> 4;
    const int rem = tl & 15;
    const int slot = (t & 96) + (kt << 4) + ((rem >> 2) & 1) * 8 + ((rem & 3) | (((rem >> 3) & 1) << 2));
#pragma unroll
    for (int i = 0; i < 8; ++i) Vp[(c0 + i) * 136 + slot] = (ushort)vv[i];
  }
  __syncthreads();

  const float* mbase = mask + (long)n * SEQ * SEQ;

  for (int mt = 0; mt < 4; ++mt) {
    // Q B-frags (normalized): col s = mt*32 + ln
    short8v qfr[2];
#pragma unroll
    for (int kt = 0; kt < 2; ++kt) {
      short8v raw = *(const short8v*)(q + base + (long)(mt * 32 + ln) * DIM + cb + kt * 16 + hi * 8);
      short8v f;
#pragma unroll
      for (int i = 0; i < 8; ++i) {
        const int c = cb + kt * 16 + hi * 8 + i;
        f[i] = (short)f2bf(bf2f((ushort)raw[i]) * qsc[c] + qbi[c]);
      }
      qfr[kt] = f;
    }

    // S^T = K_norm · Q_norm^T : st[nt] covers t = nt*32..+31 for s-col = ln
    f32x16 st[4];
#pragma unroll
    for (int nt = 0; nt < 4; ++nt)
#pragma unroll
      for (int r = 0; r < 16; ++r) st[nt][r] = 0.f;
#pragma unroll
    for (int nt = 0; nt < 4; ++nt) {
#pragma unroll
      for (int kt = 0; kt < 2; ++kt) {
        short8v raw = *(const short8v*)(k_in + base + (long)(nt * 32 + ln) * DIM + cb + kt * 16 + hi * 8);
        short8v f;
#pragma unroll
        for (int i = 0; i < 8; ++i) {
          const int c = cb + kt * 16 + hi * 8 + i;
          f[i] = (short)f2bf(bf2f((ushort)raw[i]) * ksc[c] + kbi[c]);
        }
        st[nt] = __builtin_amdgcn_mfma_f32_32x32x16_bf16(f, qfr[kt], st[nt], 0, 0, 0);
      }
    }

    // mask (reference: softmax(alpha*mask)) + in-lane softmax
    const float* mr = mbase + (long)(mt * 32 + ln) * SEQ;
    float mx = -1e30f;
#pragma unroll
    for (int nt = 0; nt < 4; ++nt)
#pragma unroll
      for (int r = 0; r < 16; ++r) {
        const int t = nt * 32 + (r & 3) + 8 * (r >> 2) + 4 * hi;
        st[nt][r] *= mr[t];
        mx = fmaxf(mx, st[nt][r]);
      }
    mx = fmaxf(mx, __shfl_xor(mx, 32));
    float sum = 0.f;
#pragma unroll
    for (int nt = 0; nt < 4; ++nt)
#pragma unroll
      for (int r = 0; r < 16; ++r) {
        const float e = __expf(st[nt][r] - mx);
        st[nt][r] = e;
        sum += e;
      }
    sum += __shfl_xor(sum, 32);
    const float inv = 1.f / sum;

    // O = P · V_raw ; P A-frags come straight from st regs
    f32x16 o;
#pragma unroll
    for (int r = 0; r < 16; ++r) o[r] = 0.f;
#pragma unroll
    for (int nt = 0; nt < 4; ++nt) {
#pragma unroll
      for (int kt = 0; kt < 2; ++kt) {
        short8v pa;
#pragma unroll
        for (int j = 0; j < 8; ++j) pa[j] = (short)f2bf(st[nt][kt * 8 + j] * inv);
        short8v vb = *(const short8v*)&Vp[(long)cc * 136 + nt * 32 + kt * 16 + hi * 8];
        o = __builtin_amdgcn_mfma_f32_32x32x16_bf16(pa, vb, o, 0, 0, 0);
      }
    }

    // epilogue: V batch-norm folded (sum P = 1): out = vs*o + vb0
#pragma unroll
    for (int r = 0; r < 16; ++r) {
      const int s = mt * 32 + (r & 3) + 8 * (r >> 2) + 4 * hi;
      out[base + (long)s * DIM + cc] = f2bf(vs * o[r] + vb0);
    }
  }
}

// ---------------------------------------------------------------------------
// out1 = LN(agg + h). agg bf16, h fp32, out bf16. One wave per row.
// ---------------------------------------------------------------------------
__global__ __launch_bounds__(256) void ln_add(
    const ushort* __restrict__ a, const float* __restrict__ b,
    const float* __restrict__ g, const float* __restrict__ bb,
    ushort* __restrict__ out)
{
  const int lane = threadIdx.x & 63;
  const int wid  = (blockIdx.x * 256 + threadIdx.x) >> 6;
  const int NW   = gridDim.x * 4;
  const int c = lane * 2;
  const float g0 = g[c], g1 = g[c + 1], be0 = bb[c], be1 = bb[c + 1];
  for (int m = wid; m < MTOT; m += NW) {
    const long off = (long)m * DIM + c;
    uint av = *(const uint*)(a + off);
    float2 hv = *(const float2*)(b + off);
    float y0 = bf2f((ushort)(av & 0xFFFFu)) + hv.x;
    float y1 = bf2f((ushort)(av >> 16))     + hv.y;
    float s = y0 + y1, sq = y0 * y0 + y1 * y1;
#pragma unroll
    for (int o = 32; o; o >>= 1) { s += __shfl_xor(s, o); sq += __shfl_xor(sq, o); }
    const float mean = s * (1.f / 128.f);
    const float var  = sq * (1.f / 128.f) - mean * mean;
    const float rs   = rsqrtf(var + EPSF);
    float o0 = (y0 - mean) * rs * g0 + be0;
    float o1 = (y1 - mean) * rs * g1 + be1;
    *(uint*)(out + off) = (uint)f2bf(o0) | ((uint)f2bf(o1) << 16);
  }
}

// ---------------------------------------------------------------------------
// h_new = LN(out1 + BN_ff(ff_raw)) + BN_skip(skip_raw). Inputs bf16, out fp32.
// FINAL=true: only rows m=n*S, compact (N,128) -> d_out.
// ---------------------------------------------------------------------------
template <bool FINAL>
__global__ __launch_bounds__(256) void fuse2_k(
    const ushort* __restrict__ t1, const ushort* __restrict__ ffr, const ushort* __restrict__ skr,
    const float* __restrict__ fst, const float* __restrict__ sst,
    const float* __restrict__ fg, const float* __restrict__ fb,
    const float* __restrict__ sg, const float* __restrict__ sb,
    const float* __restrict__ lg, const float* __restrict__ lb,
    float* __restrict__ out)
{
  const int lane = threadIdx.x & 63;
  const int c = lane * 2;
  float fs0, fbias0, fs1, fbias1, ss0, sbias0, ss1, sbias1;
  {
    float m0 = fst[c] * INV_M;
    float v0 = fst[128 + c] * INV_M - m0 * m0;
    fs0 = rsqrtf(v0 + EPSF) * fg[c];       fbias0 = fb[c] - m0 * fs0;
    float m1 = fst[c + 1] * INV_M;
    float v1 = fst[128 + c + 1] * INV_M - m1 * m1;
    fs1 = rsqrtf(v1 + EPSF) * fg[c + 1];   fbias1 = fb[c + 1] - m1 * fs1;
    float n0 = sst[c] * INV_M;
    float w0 = sst[128 + c] * INV_M - n0 * n0;
    ss0 = rsqrtf(w0 + EPSF) * sg[c];       sbias0 = sb[c] - n0 * ss0;
    float n1 = sst[c + 1] * INV_M;
    float w1 = sst[128 + c + 1] * INV_M - n1 * n1;
    ss1 = rsqrtf(w1 + EPSF) * sg[c + 1];   sbias1 = sb[c + 1] - n1 * ss1;
  }
  const float lg0 = lg[c], lg1 = lg[c + 1], lb0 = lb[c], lb1 = lb[c + 1];
  const int wid = (blockIdx.x * 256 + threadIdx.x) >> 6;
  const int NW  = gridDim.x * 4;
  const int ROWS = FINAL ? NBATCH : MTOT;
  for (int r = wid; r < ROWS; r += NW) {
    const long m   = FINAL ? (long)r * SEQ : (long)r;
    const long off = m * DIM + c;
    uint tv = *(const uint*)(t1 + off);
    uint fv = *(const uint*)(ffr + off);
    uint sv = *(const uint*)(skr + off);
    float t0 = bf2f((ushort)(tv & 0xFFFFu)), t1_ = bf2f((ushort)(tv >> 16));
    float f0 = bf2f((ushort)(fv & 0xFFFFu)), f1 = bf2f((ushort)(fv >> 16));
    float s0 = bf2f((ushort)(sv & 0xFFFFu)), s1 = bf2f((ushort)(sv >> 16));
    float y0 = t0 + f0 * fs0 + fbias0;
    float y1 = t1_ + f1 * fs1 + fbias1;
    float s = y0 + y1, sq = y0 * y0 + y1 * y1;
#pragma unroll
    for (int o = 32; o; o >>= 1) { s += __shfl_xor(s, o); sq += __shfl_xor(sq, o); }
    const float mean = s * (1.f / 128.f);
    const float var  = sq * (1.f / 128.f) - mean * mean;
    const float rs   = rsqrtf(var + EPSF);
    float o0 = (y0 - mean) * rs * lg0 + lb0 + (s0 * ss0 + sbias0);
    float o1 = (y1 - mean) * rs * lg1 + lb1 + (s1 * ss1 + sbias1);
    const long ooff = FINAL ? ((long)r * DIM + c) : off;
    *(float2*)(out + ooff) = make_float2(o0, o1);
  }
}

// ---------------------------------------------------------------------------
extern "C" void kernel_launch(void* const* d_in, const int* in_sizes, int n_in,
                              void* d_out, int out_size, void* d_ws, size_t ws_size,
                              hipStream_t stream)
{
  (void)in_sizes; (void)n_in; (void)out_size; (void)ws_size;
  const float* x    = (const float*)d_in[0];
  const float* mask = (const float*)d_in[1];
  const float* linW = (const float*)d_in[2];
  const float* ing  = (const float*)d_in[4];
  const float* inb  = (const float*)d_in[5];
  const float* qW   = (const float*)d_in[6];
  const float* qg   = (const float*)d_in[8];
  const float* qb   = (const float*)d_in[9];
  const float* kW   = (const float*)d_in[10];
  const float* kg   = (const float*)d_in[12];
  const float* kb   = (const float*)d_in[13];
  const float* vW   = (const float*)d_in[14];
  const float* vg   = (const float*)d_in[16];
  const float* vb   = (const float*)d_in[17];
  const float* lng  = (const float*)d_in[18];
  const float* lnb  = (const float*)d_in[19];
  const float* ffW  = (const float*)d_in[20];
  const float* ffg  = (const float*)d_in[22];
  const float* ffb  = (const float*)d_in[23];
  const float* skW  = (const float*)d_in[24];
  const float* skg  = (const float*)d_in[26];
  const float* skb  = (const float*)d_in[27];

  const long MD = (long)MTOT * DIM;
  float*  stats = (float*)d_ws;                 // 11 * 256 floats
  float*  h     = (float*)d_ws + 4096;          // 16 KB pad
  ushort* qbuf  = (ushort*)(h + MD);
  ushort* kbuf  = qbuf + MD;
  ushort* vbuf  = kbuf + MD;                    // total ~160.02 MB

  // bf16 swizzled weights live in the tail-unused d_out buffer (512 KB;
  // needs 360448 B; fully overwritten by fuse2_k<true> at the very end).
  ushort* Wsw = (ushort*)d_out;

  hipMemsetAsync(stats, 0, 11 * 256 * sizeof(float), stream);

  WPtrs wp;
  wp.p[0] = linW;
  wp.p[1] = qW;            wp.p[2] = kW;            wp.p[3] = vW;
  wp.p[4] = ffW;           wp.p[5] = skW;
  wp.p[6] = qW + 16384;    wp.p[7] = kW + 16384;    wp.p[8] = vW + 16384;
  wp.p[9] = ffW + 16384;   wp.p[10] = skW + 16384;
  prep_w<<<88, 256, 0, stream>>>(wp, Wsw);

  gemm_one<false, false><<<512, 256, 0, stream>>>(x, Wsw, h, stats);
  bn_apply<<<1024, 256, 0, stream>>>(h, stats, ing, inb);

  for (int l = 0; l < NLAYER; ++l) {
    const int poff = l * DIM;
    const ushort* wbase = Wsw + (1 + 5 * l) * 16384;
    float* stq = stats + (1 + 5 * l) * 256;
    float* stk = stats + (2 + 5 * l) * 256;
    float* stv = stats + (3 + 5 * l) * 256;
    float* stf = stats + (4 + 5 * l) * 256;
    float* sts = stats + (5 + 5 * l) * 256;

    gemm_qkv<<<512, 256, 0, stream>>>(h, wbase, qbuf, kbuf, vbuf, stq, stk, stv);

    attn_mfma2<<<NBATCH, 256, 0, stream>>>(
        qbuf, kbuf, vbuf, mask, stq, stk, stv,
        qg + poff, qb + poff, kg + poff, kb + poff, vg + poff, vb + poff,
        vbuf /* agg in-place */);

    gemm_one<false, true><<<512, 256, 0, stream>>>(h, wbase + 4 * 16384, qbuf, sts);  // skip

    ln_add<<<1024, 256, 0, stream>>>(vbuf, h, lng + poff, lnb + poff, kbuf);

    gemm_one<true, true><<<512, 256, 0, stream>>>(kbuf, wbase + 3 * 16384, vbuf, stf); // ff

    if (l < NLAYER - 1) {
      fuse2_k<false><<<1024, 256, 0, stream>>>(
          kbuf, vbuf, qbuf, stf, sts,
          ffg + poff, ffb + poff, skg + poff, skb + poff,
          lng + poff, lnb + poff, h);
    } else {
      fuse2_k<true><<<64, 256, 0, stream>>>(
          kbuf, vbuf, qbuf, stf, sts,
          ffg + poff, ffb + poff, skg + poff, skb + poff,
          lng + poff, lnb + poff, (float*)d_out);
    }
  }
}

// Round 6
// 646.009 us; speedup vs baseline: 3.0064x; 1.1679x over previous
//
#include <hip/hip_runtime.h>
#include <hip/hip_bf16.h>

// ToyMDNN on MI355X — round 6.
//  * mask bit-packed once (64MB fp32 -> 2MB uint4/row); attn reads 16B/lane.
//  * attn: normalized K-fragments cached in registers across mt loop (r4
//    pattern) -> K read 1x from HBM instead of 4x.
//  * skip GEMM fused into QKV kernel (4 outputs, A read once, step loop
//    fully unrolled -> static indexing). sbuf added (~194MB ws total).
// N=1024 S=128 D=128 H=4 C=32 L=2. GEMM biases cancel through batch-norm.

typedef __attribute__((ext_vector_type(8))) short short8v;
typedef __attribute__((ext_vector_type(16))) float f32x16;

#define NBATCH 1024
#define SEQ    128
#define DIM    128
#define NLAYER 2
#define MTOT   (NBATCH*SEQ)
#define EPSF   1e-5f
#define INV_M  (1.0f/131072.0f)

__device__ __forceinline__ float bf2f(ushort s) {
  return __uint_as_float(((uint)s) << 16);
}
__device__ __forceinline__ ushort f2bf(float f) {
  uint u = __float_as_uint(f);
  return (ushort)((u + 0x7FFFu + ((u >> 16) & 1u)) >> 16);
}

struct WPtrs { const float* p[11]; };

// ---------------------------------------------------------------------------
// One-time: 11 weight matrices fp32 -> bf16, swizzled GEMM-LDS layout.
// ---------------------------------------------------------------------------
__global__ __launch_bounds__(256) void prep_w(WPtrs wp, ushort* __restrict__ dst)
{
  const int gid = blockIdx.x * 256 + threadIdx.x;   // 88*256 = 22528 = 11*2048
  const int m = gid >> 11;
  const int rem = gid & 2047;
  const int j = rem >> 4, kc = rem & 15;
  const float* src = wp.p[m];
  float4 a = *(const float4*)(src + j * DIM + kc * 8);
  float4 b = *(const float4*)(src + j * DIM + kc * 8 + 4);
  short8v v;
  v[0] = (short)f2bf(a.x); v[1] = (short)f2bf(a.y);
  v[2] = (short)f2bf(a.z); v[3] = (short)f2bf(a.w);
  v[4] = (short)f2bf(b.x); v[5] = (short)f2bf(b.y);
  v[6] = (short)f2bf(b.z); v[7] = (short)f2bf(b.w);
  *(short8v*)(dst + m * 16384 + j * 128 + ((kc * 8) ^ ((j & 7) << 3))) = v;
}

// ---------------------------------------------------------------------------
// One-time: pack 0/1 fp32 mask rows into 128-bit rows (uint4). Bit t of the
// row = word[t>>5] >> (t&31). Ballot-based, coalesced reads.
// ---------------------------------------------------------------------------
__global__ __launch_bounds__(256) void pack_mask(
    const float* __restrict__ mask, uint4* __restrict__ mb)
{
  const int lane = threadIdx.x & 63;
  const int wv   = (blockIdx.x * 256 + threadIdx.x) >> 6;
  const int NW   = gridDim.x * 4;
  for (int row = wv; row < MTOT; row += NW) {
    const float a = mask[(long)row * SEQ + lane];
    const float b = mask[(long)row * SEQ + 64 + lane];
    const unsigned long long lo = __ballot(a != 0.f);
    const unsigned long long hi = __ballot(b != 0.f);
    if (lane == 0) {
      uint4 w;
      w.x = (uint)lo; w.y = (uint)(lo >> 32);
      w.z = (uint)hi; w.w = (uint)(hi >> 32);
      mb[row] = w;
    }
  }
}

// ---------------------------------------------------------------------------
// Single GEMM: out[m][j] = sum_k A[m][k]*W[j][k] + column stats.
// Grid 512, 2 tiles of 128 rows per block. W (bf16, pre-swizzled) staged once.
// ---------------------------------------------------------------------------
template<bool ABF16, bool OBF16>
__global__ __launch_bounds__(256) void gemm_one(
    const void* __restrict__ Ap, const ushort* __restrict__ Wsw,
    void* __restrict__ outp, float* __restrict__ stats)
{
  __shared__ ushort Wt[16384];
  __shared__ float csum[128], csq[128];
  const int tid = threadIdx.x;
  const int lane = tid & 63, wid = tid >> 6;
  const int hi = lane >> 5, ln = lane & 31;

  for (int i = tid; i < 2048; i += 256)
    ((short8v*)Wt)[i] = ((const short8v*)Wsw)[i];
  if (tid < 128) { csum[tid] = 0.f; csq[tid] = 0.f; }
  __syncthreads();

  float ps[4], pq[4];
#pragma unroll
  for (int nt = 0; nt < 4; ++nt) { ps[nt] = 0.f; pq[nt] = 0.f; }

#pragma unroll
  for (int t = 0; t < 2; ++t) {
    const long m0 = ((long)blockIdx.x * 2 + t) * 128;
    const long arow = m0 + wid * 32 + ln;
    short8v afr[8];
    if constexpr (ABF16) {
      const ushort* ar = (const ushort*)Ap + arow * DIM + hi * 8;
#pragma unroll
      for (int kt = 0; kt < 8; ++kt) afr[kt] = *(const short8v*)(ar + kt * 16);
    } else {
      const float* ar = (const float*)Ap + arow * DIM + hi * 8;
#pragma unroll
      for (int kt = 0; kt < 8; ++kt) {
        float4 a0 = *(const float4*)(ar + kt * 16);
        float4 a1 = *(const float4*)(ar + kt * 16 + 4);
        short8v v;
        v[0] = (short)f2bf(a0.x); v[1] = (short)f2bf(a0.y);
        v[2] = (short)f2bf(a0.z); v[3] = (short)f2bf(a0.w);
        v[4] = (short)f2bf(a1.x); v[5] = (short)f2bf(a1.y);
        v[6] = (short)f2bf(a1.z); v[7] = (short)f2bf(a1.w);
        afr[kt] = v;
      }
    }

    f32x16 acc[4];
#pragma unroll
    for (int nt = 0; nt < 4; ++nt)
#pragma unroll
      for (int r = 0; r < 16; ++r) acc[nt][r] = 0.f;
#pragma unroll
    for (int kt = 0; kt < 8; ++kt)
#pragma unroll
      for (int nt = 0; nt < 4; ++nt) {
        short8v b = *(const short8v*)&Wt[((nt * 32 + ln) * 128 + kt * 16 + hi * 8) ^ ((ln & 7) << 3)];
        acc[nt] = __builtin_amdgcn_mfma_f32_32x32x16_bf16(afr[kt], b, acc[nt], 0, 0, 0);
      }

#pragma unroll
    for (int nt = 0; nt < 4; ++nt) {
      const int col = nt * 32 + ln;
#pragma unroll
      for (int r = 0; r < 16; ++r) {
        const float v = acc[nt][r];
        ps[nt] += v; pq[nt] += v * v;
        const long row = m0 + wid * 32 + (r & 3) + 8 * (r >> 2) + 4 * hi;
        if constexpr (OBF16) ((ushort*)outp)[row * DIM + col] = f2bf(v);
        else                 ((float*)outp)[row * DIM + col] = v;
      }
    }
  }

#pragma unroll
  for (int nt = 0; nt < 4; ++nt) {
    ps[nt] += __shfl_xor(ps[nt], 32);
    pq[nt] += __shfl_xor(pq[nt], 32);
  }
  if (hi == 0) {
#pragma unroll
    for (int nt = 0; nt < 4; ++nt) {
      atomicAdd(&csum[nt * 32 + ln], ps[nt]);
      atomicAdd(&csq[nt * 32 + ln], pq[nt]);
    }
  }
  __syncthreads();
  if (tid < 128) {
    atomicAdd(&stats[tid],       csum[tid]);
    atomicAdd(&stats[128 + tid], csq[tid]);
  }
}

// ---------------------------------------------------------------------------
// Fused Q/K/V/SKIP GEMM: A (fp32 h) read once per tile; 4 weight matrices
// (q,k,v,skip at Wsw offsets 0,1,2,4) cycled through a double-buffered LDS
// stage. Step loop fully unrolled -> all w-indexing static (no scratch).
// ---------------------------------------------------------------------------
__global__ __launch_bounds__(256) void gemm_qkvs(
    const float* __restrict__ A, const ushort* __restrict__ Wsw,
    ushort* __restrict__ o0, ushort* __restrict__ o1,
    ushort* __restrict__ o2, ushort* __restrict__ o3,
    float* __restrict__ st0, float* __restrict__ st1,
    float* __restrict__ st2, float* __restrict__ st3)
{
  __shared__ ushort Wt[2][16384];
  __shared__ float csum[128], csq[128];
  const int tid = threadIdx.x;
  const int lane = tid & 63, wid = tid >> 6;
  const int hi = lane >> 5, ln = lane & 31;

  for (int i = tid; i < 2048; i += 256)
    ((short8v*)Wt[0])[i] = ((const short8v*)Wsw)[i];
  if (tid < 128) { csum[tid] = 0.f; csq[tid] = 0.f; }

  float ps[4][4], pq[4][4];
#pragma unroll
  for (int w = 0; w < 4; ++w)
#pragma unroll
    for (int nt = 0; nt < 4; ++nt) { ps[w][nt] = 0.f; pq[w][nt] = 0.f; }

  __syncthreads();

  short8v afr[8];
#pragma unroll
  for (int step = 0; step < 8; ++step) {
    const int t = step >> 2, w = step & 3;
    const long m0 = ((long)blockIdx.x * 2 + t) * 128;
    if (w == 0) {
      const float* ar = A + (m0 + wid * 32 + ln) * DIM + hi * 8;
#pragma unroll
      for (int kt = 0; kt < 8; ++kt) {
        float4 a0 = *(const float4*)(ar + kt * 16);
        float4 a1 = *(const float4*)(ar + kt * 16 + 4);
        short8v v;
        v[0] = (short)f2bf(a0.x); v[1] = (short)f2bf(a0.y);
        v[2] = (short)f2bf(a0.z); v[3] = (short)f2bf(a0.w);
        v[4] = (short)f2bf(a1.x); v[5] = (short)f2bf(a1.y);
        v[6] = (short)f2bf(a1.z); v[7] = (short)f2bf(a1.w);
        afr[kt] = v;
      }
    }
    if (step < 7) {
      const int wn = (step + 1) & 3;
      const int mwn = (wn == 3) ? 4 : wn;             // q,k,v,skip -> 0,1,2,4
      const short8v* src = (const short8v*)(Wsw + mwn * 16384);
      short8v* dst = (short8v*)Wt[(step + 1) & 1];
      for (int i = tid; i < 2048; i += 256) dst[i] = src[i];
    }

    f32x16 acc[4];
#pragma unroll
    for (int nt = 0; nt < 4; ++nt)
#pragma unroll
      for (int r = 0; r < 16; ++r) acc[nt][r] = 0.f;
    const ushort* wt = Wt[step & 1];
#pragma unroll
    for (int kt = 0; kt < 8; ++kt)
#pragma unroll
      for (int nt = 0; nt < 4; ++nt) {
        short8v b = *(const short8v*)&wt[((nt * 32 + ln) * 128 + kt * 16 + hi * 8) ^ ((ln & 7) << 3)];
        acc[nt] = __builtin_amdgcn_mfma_f32_32x32x16_bf16(afr[kt], b, acc[nt], 0, 0, 0);
      }

    ushort* outp = (w == 0) ? o0 : (w == 1) ? o1 : (w == 2) ? o2 : o3;
#pragma unroll
    for (int nt = 0; nt < 4; ++nt) {
      const int col = nt * 32 + ln;
#pragma unroll
      for (int r = 0; r < 16; ++r) {
        const float v = acc[nt][r];
        ps[w][nt] += v; pq[w][nt] += v * v;
        const long row = m0 + wid * 32 + (r & 3) + 8 * (r >> 2) + 4 * hi;
        outp[row * DIM + col] = f2bf(v);
      }
    }
    __syncthreads();
  }

  // stats: one reduction round per w
#pragma unroll
  for (int w = 0; w < 4; ++w) {
    float* st = (w == 0) ? st0 : (w == 1) ? st1 : (w == 2) ? st2 : st3;
    float lps[4], lpq[4];
#pragma unroll
    for (int nt = 0; nt < 4; ++nt) {
      lps[nt] = ps[w][nt] + __shfl_xor(ps[w][nt], 32);
      lpq[nt] = pq[w][nt] + __shfl_xor(pq[w][nt], 32);
    }
    if (hi == 0) {
#pragma unroll
      for (int nt = 0; nt < 4; ++nt) {
        atomicAdd(&csum[nt * 32 + ln], lps[nt]);
        atomicAdd(&csq[nt * 32 + ln],  lpq[nt]);
      }
    }
    __syncthreads();
    if (tid < 128) {
      atomicAdd(&st[tid],       csum[tid]);
      atomicAdd(&st[128 + tid], csq[tid]);
      csum[tid] = 0.f; csq[tid] = 0.f;
    }
    __syncthreads();
  }
}

// ---------------------------------------------------------------------------
// In-place BN apply for h (fp32).
// ---------------------------------------------------------------------------
__global__ __launch_bounds__(256) void bn_apply(
    float* __restrict__ x, const float* __restrict__ st,
    const float* __restrict__ g, const float* __restrict__ b)
{
  __shared__ float sc[128], bi[128];
  const int tid = threadIdx.x;
  if (tid < 128) {
    float mean = st[tid] * INV_M;
    float var  = st[128 + tid] * INV_M - mean * mean;
    float s = rsqrtf(var + EPSF) * g[tid];
    sc[tid] = s;
    bi[tid] = b[tid] - mean * s;
  }
  __syncthreads();
  const long total4 = (long)MTOT * DIM / 4;
  for (long i = (long)blockIdx.x * 256 + tid; i < total4; i += (long)gridDim.x * 256) {
    float4 vv = ((const float4*)x)[i];
    const int c = (int)((i * 4) & 127);
    vv.x = vv.x * sc[c + 0] + bi[c + 0];
    vv.y = vv.y * sc[c + 1] + bi[c + 1];
    vv.z = vv.z * sc[c + 2] + bi[c + 2];
    vv.w = vv.w * sc[c + 3] + bi[c + 3];
    ((float4*)x)[i] = vv;
  }
}

// ---------------------------------------------------------------------------
// Attention, swapped-QK^T form. One block per n; wave = head.
// Normalized K-fragments CACHED in registers across the 4 row-tiles (K read
// once from HBM). Mask applied from the 128-bit packed rows. Softmax in-lane.
// V raw in LDS; V batch-norm folded into the epilogue via sum(P)=1.
// ---------------------------------------------------------------------------
__global__ __launch_bounds__(256, 4) void attn_mfma3(
    const ushort* __restrict__ q, const ushort* __restrict__ k_in, const ushort* v_in,
    const uint4* __restrict__ mb,
    const float* __restrict__ qst, const float* __restrict__ kst, const float* __restrict__ vst,
    const float* __restrict__ qg, const float* __restrict__ qbb,
    const float* __restrict__ kg, const float* __restrict__ kbb,
    const float* __restrict__ vg, const float* __restrict__ vbb,
    ushort* out)
{
  __shared__ ushort Vp[128 * 136];    // [c][slot(t)] raw bf16
  __shared__ float qsc[128], qbi[128], ksc[128], kbi[128];

  const int tid = threadIdx.x;
  const int lane = tid & 63, wid = tid >> 6;
  const int hi = lane >> 5, ln = lane & 31;
  const int n = blockIdx.x;
  const long base = (long)n * SEQ * DIM;
  const int cb = wid * 32;

  if (tid < 128) {
    const int c = tid;
    float m, v, s;
    m = qst[c] * INV_M; v = qst[128 + c] * INV_M - m * m;
    s = rsqrtf(v + EPSF) * qg[c];  qsc[c] = s; qbi[c] = qbb[c] - m * s;
    m = kst[c] * INV_M; v = kst[128 + c] * INV_M - m * m;
    s = rsqrtf(v + EPSF) * kg[c];  ksc[c] = s; kbi[c] = kbb[c] - m * s;
  }
  const int cc = cb + ln;
  float vs, vb0;
  {
    float m = vst[cc] * INV_M;
    float v = vst[128 + cc] * INV_M - m * m;
    vs = rsqrtf(v + EPSF) * vg[cc];
    vb0 = vbb[cc] - m * vs;
  }

  // stage V raw into permuted slots: Vp[c][slot(t)] = V[t][c]
  for (int it = 0; it < 8; ++it) {
    const int idx = it * 256 + tid;
    const int t = idx & 127, c0 = (idx >> 7) * 8;
    short8v vv = *(const short8v*)(v_in + base + (long)t * DIM + c0);
    const int tl = t & 31;
    const int kt = tl >> 4;
    const int rem = tl & 15;
    const int slot = (t & 96) + (kt << 4) + ((rem >> 2) & 1) * 8 + ((rem & 3) | (((rem >> 3) & 1) << 2));
#pragma unroll
    for (int i = 0; i < 8; ++i) Vp[(c0 + i) * 136 + slot] = (ushort)vv[i];
  }
  __syncthreads();

  // K B-fragments (normalized), cached for ALL row-tiles (K read once)
  short8v kfr[4][2];
#pragma unroll
  for (int nt = 0; nt < 4; ++nt)
#pragma unroll
    for (int kt = 0; kt < 2; ++kt) {
      short8v raw = *(const short8v*)(k_in + base + (long)(nt * 32 + ln) * DIM + cb + kt * 16 + hi * 8);
      short8v f;
#pragma unroll
      for (int i = 0; i < 8; ++i) {
        const int c = cb + kt * 16 + hi * 8 + i;
        f[i] = (short)f2bf(bf2f((ushort)raw[i]) * ksc[c] + kbi[c]);
      }
      kfr[nt][kt] = f;
    }

  for (int mt = 0; mt < 4; ++mt) {
    // Q B-frags (normalized): col s = mt*32 + ln
    short8v qfr[2];
#pragma unroll
    for (int kt = 0; kt < 2; ++kt) {
      short8v raw = *(const short8v*)(q + base + (long)(mt * 32 + ln) * DIM + cb + kt * 16 + hi * 8);
      short8v f;
#pragma unroll
      for (int i = 0; i < 8; ++i) {
        const int c = cb + kt * 16 + hi * 8 + i;
        f[i] = (short)f2bf(bf2f((ushort)raw[i]) * qsc[c] + qbi[c]);
      }
      qfr[kt] = f;
    }

    // S^T = K_norm · Q_norm^T : st[nt] covers t = nt*32..+31 for s-col = ln
    f32x16 st[4];
#pragma unroll
    for (int nt = 0; nt < 4; ++nt)
#pragma unroll
      for (int r = 0; r < 16; ++r) st[nt][r] = 0.f;
#pragma unroll
    for (int nt = 0; nt < 4; ++nt) {
      st[nt] = __builtin_amdgcn_mfma_f32_32x32x16_bf16(kfr[nt][0], qfr[0], st[nt], 0, 0, 0);
      st[nt] = __builtin_amdgcn_mfma_f32_32x32x16_bf16(kfr[nt][1], qfr[1], st[nt], 0, 0, 0);
    }

    // mask from packed bits (softmax(alpha*mask) semantics) + in-lane softmax
    const uint4 bw = mb[(long)n * SEQ + mt * 32 + ln];
    float mx = -1e30f;
#pragma unroll
    for (int nt = 0; nt < 4; ++nt) {
      const uint word = (nt == 0) ? bw.x : (nt == 1) ? bw.y : (nt == 2) ? bw.z : bw.w;
#pragma unroll
      for (int r = 0; r < 16; ++r) {
        const int crow = (r & 3) + 8 * (r >> 2) + 4 * hi;
        st[nt][r] = ((word >> crow) & 1u) ? st[nt][r] : 0.f;
        mx = fmaxf(mx, st[nt][r]);
      }
    }
    mx = fmaxf(mx, __shfl_xor(mx, 32));
    float sum = 0.f;
#pragma unroll
    for (int nt = 0; nt < 4; ++nt)
#pragma unroll
      for (int r = 0; r < 16; ++r) {
        const float e = __expf(st[nt][r] - mx);
        st[nt][r] = e;
        sum += e;
      }
    sum += __shfl_xor(sum, 32);
    const float inv = 1.f / sum;

    // O = P · V_raw ; P A-frags straight from st regs
    f32x16 o;
#pragma unroll
    for (int r = 0; r < 16; ++r) o[r] = 0.f;
#pragma unroll
    for (int nt = 0; nt < 4; ++nt) {
#pragma unroll
      for (int kt = 0; kt < 2; ++kt) {
        short8v pa;
#pragma unroll
        for (int j = 0; j < 8; ++j) pa[j] = (short)f2bf(st[nt][kt * 8 + j] * inv);
        short8v vb = *(const short8v*)&Vp[(long)cc * 136 + nt * 32 + kt * 16 + hi * 8];
        o = __builtin_amdgcn_mfma_f32_32x32x16_bf16(pa, vb, o, 0, 0, 0);
      }
    }

    // epilogue: V batch-norm folded (sum P = 1): out = vs*o + vb0
#pragma unroll
    for (int r = 0; r < 16; ++r) {
      const int s = mt * 32 + (r & 3) + 8 * (r >> 2) + 4 * hi;
      out[base + (long)s * DIM + cc] = f2bf(vs * o[r] + vb0);
    }
  }
}

// ---------------------------------------------------------------------------
// out1 = LN(agg + h). agg bf16, h fp32, out bf16. One wave per row.
// ---------------------------------------------------------------------------
__global__ __launch_bounds__(256) void ln_add(
    const ushort* __restrict__ a, const float* __restrict__ b,
    const float* __restrict__ g, const float* __restrict__ bb,
    ushort* __restrict__ out)
{
  const int lane = threadIdx.x & 63;
  const int wid  = (blockIdx.x * 256 + threadIdx.x) >> 6;
  const int NW   = gridDim.x * 4;
  const int c = lane * 2;
  const float g0 = g[c], g1 = g[c + 1], be0 = bb[c], be1 = bb[c + 1];
  for (int m = wid; m < MTOT; m += NW) {
    const long off = (long)m * DIM + c;
    uint av = *(const uint*)(a + off);
    float2 hv = *(const float2*)(b + off);
    float y0 = bf2f((ushort)(av & 0xFFFFu)) + hv.x;
    float y1 = bf2f((ushort)(av >> 16))     + hv.y;
    float s = y0 + y1, sq = y0 * y0 + y1 * y1;
#pragma unroll
    for (int o = 32; o; o >>= 1) { s += __shfl_xor(s, o); sq += __shfl_xor(sq, o); }
    const float mean = s * (1.f / 128.f);
    const float var  = sq * (1.f / 128.f) - mean * mean;
    const float rs   = rsqrtf(var + EPSF);
    float o0 = (y0 - mean) * rs * g0 + be0;
    float o1 = (y1 - mean) * rs * g1 + be1;
    *(uint*)(out + off) = (uint)f2bf(o0) | ((uint)f2bf(o1) << 16);
  }
}

// ---------------------------------------------------------------------------
// h_new = LN(out1 + BN_ff(ff_raw)) + BN_skip(skip_raw). Inputs bf16, out fp32.
// FINAL=true: only rows m=n*S, compact (N,128) -> d_out.
// ---------------------------------------------------------------------------
template <bool FINAL>
__global__ __launch_bounds__(256) void fuse2_k(
    const ushort* __restrict__ t1, const ushort* __restrict__ ffr, const ushort* __restrict__ skr,
    const float* __restrict__ fst, const float* __restrict__ sst,
    const float* __restrict__ fg, const float* __restrict__ fb,
    const float* __restrict__ sg, const float* __restrict__ sb,
    const float* __restrict__ lg, const float* __restrict__ lb,
    float* __restrict__ out)
{
  const int lane = threadIdx.x & 63;
  const int c = lane * 2;
  float fs0, fbias0, fs1, fbias1, ss0, sbias0, ss1, sbias1;
  {
    float m0 = fst[c] * INV_M;
    float v0 = fst[128 + c] * INV_M - m0 * m0;
    fs0 = rsqrtf(v0 + EPSF) * fg[c];       fbias0 = fb[c] - m0 * fs0;
    float m1 = fst[c + 1] * INV_M;
    float v1 = fst[128 + c + 1] * INV_M - m1 * m1;
    fs1 = rsqrtf(v1 + EPSF) * fg[c + 1];   fbias1 = fb[c + 1] - m1 * fs1;
    float n0 = sst[c] * INV_M;
    float w0 = sst[128 + c] * INV_M - n0 * n0;
    ss0 = rsqrtf(w0 + EPSF) * sg[c];       sbias0 = sb[c] - n0 * ss0;
    float n1 = sst[c + 1] * INV_M;
    float w1 = sst[128 + c + 1] * INV_M - n1 * n1;
    ss1 = rsqrtf(w1 + EPSF) * sg[c + 1];   sbias1 = sb[c + 1] - n1 * ss1;
  }
  const float lg0 = lg[c], lg1 = lg[c + 1], lb0 = lb[c], lb1 = lb[c + 1];
  const int wid = (blockIdx.x * 256 + threadIdx.x) >> 6;
  const int NW  = gridDim.x * 4;
  const int ROWS = FINAL ? NBATCH : MTOT;
  for (int r = wid; r < ROWS; r += NW) {
    const long m   = FINAL ? (long)r * SEQ : (long)r;
    const long off = m * DIM + c;
    uint tv = *(const uint*)(t1 + off);
    uint fv = *(const uint*)(ffr + off);
    uint sv = *(const uint*)(skr + off);
    float t0 = bf2f((ushort)(tv & 0xFFFFu)), t1_ = bf2f((ushort)(tv >> 16));
    float f0 = bf2f((ushort)(fv & 0xFFFFu)), f1 = bf2f((ushort)(fv >> 16));
    float s0 = bf2f((ushort)(sv & 0xFFFFu)), s1 = bf2f((ushort)(sv >> 16));
    float y0 = t0 + f0 * fs0 + fbias0;
    float y1 = t1_ + f1 * fs1 + fbias1;
    float s = y0 + y1, sq = y0 * y0 + y1 * y1;
#pragma unroll
    for (int o = 32; o; o >>= 1) { s += __shfl_xor(s, o); sq += __shfl_xor(sq, o); }
    const float mean = s * (1.f / 128.f);
    const float var  = sq * (1.f / 128.f) - mean * mean;
    const float rs   = rsqrtf(var + EPSF);
    float o0 = (y0 - mean) * rs * lg0 + lb0 + (s0 * ss0 + sbias0);
    float o1 = (y1 - mean) * rs * lg1 + lb1 + (s1 * ss1 + sbias1);
    const long ooff = FINAL ? ((long)r * DIM + c) : off;
    *(float2*)(out + ooff) = make_float2(o0, o1);
  }
}

// ---------------------------------------------------------------------------
extern "C" void kernel_launch(void* const* d_in, const int* in_sizes, int n_in,
                              void* d_out, int out_size, void* d_ws, size_t ws_size,
                              hipStream_t stream)
{
  (void)in_sizes; (void)n_in; (void)out_size; (void)ws_size;
  const float* x    = (const float*)d_in[0];
  const float* mask = (const float*)d_in[1];
  const float* linW = (const float*)d_in[2];
  const float* ing  = (const float*)d_in[4];
  const float* inb  = (const float*)d_in[5];
  const float* qW   = (const float*)d_in[6];
  const float* qg   = (const float*)d_in[8];
  const float* qb   = (const float*)d_in[9];
  const float* kW   = (const float*)d_in[10];
  const float* kg   = (const float*)d_in[12];
  const float* kb   = (const float*)d_in[13];
  const float* vW   = (const float*)d_in[14];
  const float* vg   = (const float*)d_in[16];
  const float* vb   = (const float*)d_in[17];
  const float* lng  = (const float*)d_in[18];
  const float* lnb  = (const float*)d_in[19];
  const float* ffW  = (const float*)d_in[20];
  const float* ffg  = (const float*)d_in[22];
  const float* ffb  = (const float*)d_in[23];
  const float* skW  = (const float*)d_in[24];
  const float* skg  = (const float*)d_in[26];
  const float* skb  = (const float*)d_in[27];

  const long MD = (long)MTOT * DIM;
  float*  stats = (float*)d_ws;                 // 11*256 floats
  float*  h     = (float*)d_ws + 4096;          // 16 KB pad
  ushort* qbuf  = (ushort*)(h + MD);
  ushort* kbuf  = qbuf + MD;
  ushort* vbuf  = kbuf + MD;
  ushort* sbuf  = vbuf + MD;
  uint4*  mbits = (uint4*)(sbuf + MD);          // 131072 * 16 B = 2 MB
                                                // total ~194 MB

  // bf16 swizzled weights live in d_out (needs 352 KB of 512 KB; fully
  // overwritten by fuse2_k<true> at the very end).
  ushort* Wsw = (ushort*)d_out;

  hipMemsetAsync(stats, 0, 11 * 256 * sizeof(float), stream);

  WPtrs wp;
  wp.p[0] = linW;
  wp.p[1] = qW;            wp.p[2] = kW;            wp.p[3] = vW;
  wp.p[4] = ffW;           wp.p[5] = skW;
  wp.p[6] = qW + 16384;    wp.p[7] = kW + 16384;    wp.p[8] = vW + 16384;
  wp.p[9] = ffW + 16384;   wp.p[10] = skW + 16384;
  prep_w<<<88, 256, 0, stream>>>(wp, Wsw);
  pack_mask<<<512, 256, 0, stream>>>(mask, mbits);

  gemm_one<false, false><<<512, 256, 0, stream>>>(x, Wsw, h, stats);
  bn_apply<<<1024, 256, 0, stream>>>(h, stats, ing, inb);

  for (int l = 0; l < NLAYER; ++l) {
    const int poff = l * DIM;
    const ushort* wbase = Wsw + (1 + 5 * l) * 16384;
    float* stq = stats + (1 + 5 * l) * 256;
    float* stk = stats + (2 + 5 * l) * 256;
    float* stv = stats + (3 + 5 * l) * 256;
    float* stf = stats + (4 + 5 * l) * 256;
    float* sts = stats + (5 + 5 * l) * 256;

    gemm_qkvs<<<512, 256, 0, stream>>>(h, wbase, qbuf, kbuf, vbuf, sbuf,
                                       stq, stk, stv, sts);

    attn_mfma3<<<NBATCH, 256, 0, stream>>>(
        qbuf, kbuf, vbuf, mbits, stq, stk, stv,
        qg + poff, qb + poff, kg + poff, kb + poff, vg + poff, vb + poff,
        vbuf /* agg in-place */);

    ln_add<<<1024, 256, 0, stream>>>(vbuf, h, lng + poff, lnb + poff, kbuf);

    gemm_one<true, true><<<512, 256, 0, stream>>>(kbuf, wbase + 3 * 16384, vbuf, stf); // ff

    if (l < NLAYER - 1) {
      fuse2_k<false><<<1024, 256, 0, stream>>>(
          kbuf, vbuf, sbuf, stf, sts,
          ffg + poff, ffb + poff, skg + poff, skb + poff,
          lng + poff, lnb + poff, h);
    } else {
      fuse2_k<true><<<64, 256, 0, stream>>>(
          kbuf, vbuf, sbuf, stf, sts,
          ffg + poff, ffb + poff, skg + poff, skb + poff,
          lng + poff, lnb + poff, (float*)d_out);
    }
  }
}